// Round 2
// baseline (928.156 us; speedup 1.0000x reference)
//
#include <hip/hip_runtime.h>
#include <hip/hip_bf16.h>

#define NNODES 50000
#define NEDGES 800000
#define HID 256
#define BN_EPS 1e-5f

typedef __attribute__((ext_vector_type(8))) short short8v;
typedef __attribute__((ext_vector_type(4))) float f32x4;

// ---------------- CSR build ----------------
__global__ void k_zero(int* p, int n) {
    int i = blockIdx.x * blockDim.x + threadIdx.x;
    if (i < n) p[i] = 0;
}

__global__ void k_count(const int* __restrict__ ei, int* __restrict__ cnt, int nE) {
    int e = blockIdx.x * blockDim.x + threadIdx.x;
    if (e < nE) atomicAdd(&cnt[ei[nE + e]], 1);   // dst = ei[E + e]
}

// single block, 1024 threads: exclusive scan of counts -> rowptr; cursor[i]=start
__global__ void k_scan(int* __restrict__ cursor, int* __restrict__ rowptr, int n, int nE) {
    __shared__ int sums[1024];
    int tid = threadIdx.x;
    int per = (n + 1023) >> 10;
    int start = tid * per;
    int end = start + per; if (end > n) end = n;
    int s = 0;
    for (int i = start; i < end; i++) s += cursor[i];
    sums[tid] = s;
    __syncthreads();
    for (int off = 1; off < 1024; off <<= 1) {
        int v = (tid >= off) ? sums[tid - off] : 0;
        __syncthreads();
        sums[tid] += v;
        __syncthreads();
    }
    int run = sums[tid] - s;   // exclusive prefix
    for (int i = start; i < end; i++) {
        int c = cursor[i];
        rowptr[i] = run;
        cursor[i] = run;
        run += c;
    }
    if (tid == 0) rowptr[n] = nE;
}

__global__ void k_fill(const int* __restrict__ ei, int* __restrict__ cursor,
                       int* __restrict__ col, int nE) {
    int e = blockIdx.x * blockDim.x + threadIdx.x;
    if (e < nE) {
        int p = atomicAdd(&cursor[ei[nE + e]], 1);
        col[p] = ei[e];   // src
    }
}

// ---------------- cast f32 -> bf16 ----------------
__global__ void k_cast(const float* __restrict__ in, __hip_bfloat16* __restrict__ out, int n) {
    int i = blockIdx.x * blockDim.x + threadIdx.x;
    int base = i * 4;
    if (base + 3 < n) {
        float4 v = *(const float4*)(in + base);
        out[base + 0] = __float2bfloat16(v.x);
        out[base + 1] = __float2bfloat16(v.y);
        out[base + 2] = __float2bfloat16(v.z);
        out[base + 3] = __float2bfloat16(v.w);
    } else {
        for (int j = base; j < n; j++) out[j] = __float2bfloat16(in[j]);
    }
}

// ---------------- weight transpose: W[K][256] f32 -> Wt[256][K] bf16 ----------------
__global__ void k_transpose(const float* __restrict__ W,
                            __hip_bfloat16* __restrict__ Wt, int K) {
    int i = blockIdx.x * blockDim.x + threadIdx.x;
    if (i < K * HID) {
        int k = i >> 8;        // /256
        int nn = i & 255;
        Wt[nn * K + k] = __float2bfloat16(W[i]);
    }
}

// ---------------- mean aggregation (bf16 in, bf16 out): one wave per node ----
// F = bf16 features per lane (2 for d=128, 4 for d=256); D = F*64
template <int F>
__global__ void k_mean(const __hip_bfloat16* __restrict__ xin,
                       const int* __restrict__ rowptr, const int* __restrict__ col,
                       __hip_bfloat16* __restrict__ mean, int n) {
    int gw = (blockIdx.x * blockDim.x + threadIdx.x) >> 6;
    int lane = threadIdx.x & 63;
    if (gw >= n) return;
    int beg = rowptr[gw], end = rowptr[gw + 1];
    constexpr int D = F * 64;
    float acc[F];
#pragma unroll
    for (int j = 0; j < F; j++) acc[j] = 0.f;
    const unsigned int* base = (const unsigned int*)xin;
    for (int p = beg; p < end; p++) {
        int s = col[p];
        int off = (s * D + lane * F) >> 1;   // in uint (2x bf16) units
        if (F == 4) {
            uint2 v = *(const uint2*)(base + off);
            acc[0] += __uint_as_float(v.x << 16);
            acc[1] += __uint_as_float(v.x & 0xffff0000u);
            acc[2] += __uint_as_float(v.y << 16);
            acc[3] += __uint_as_float(v.y & 0xffff0000u);
        } else {
            unsigned int v = base[off];
            acc[0] += __uint_as_float(v << 16);
            acc[1] += __uint_as_float(v & 0xffff0000u);
        }
    }
    float inv = (end > beg) ? 1.f / (float)(end - beg) : 0.f;
#pragma unroll
    for (int j = 0; j < F; j++)
        mean[(size_t)gw * D + lane * F + j] = __float2bfloat16(acc[j] * inv);
}

// ---------------- fused GEMM + BN (+ReLU) ----------------
// out[n,256] = act( (A1@W1 + A2@W2 + bl - rm) * g*rsqrt(rv+eps) + b )
// A1,A2 bf16 [n,K]; W?t bf16 [256,K] (transposed); BN params f32; out f32 or bf16
template <int K, typename OutT, int RELU>
__launch_bounds__(256)
__global__ void k_gemm(const __hip_bfloat16* __restrict__ A1,
                       const __hip_bfloat16* __restrict__ A2,
                       const __hip_bfloat16* __restrict__ W1t,
                       const __hip_bfloat16* __restrict__ W2t,
                       const float* __restrict__ bl,
                       const float* __restrict__ g,
                       const float* __restrict__ bb,
                       const float* __restrict__ rm,
                       const float* __restrict__ rv,
                       OutT* __restrict__ out, int n) {
    int wave = threadIdx.x >> 6;
    int lane = threadIdx.x & 63;
    int quad = lane >> 4;
    int ml = lane & 15;
    int row_base = blockIdx.x * 64 + wave * 16;
    int arow = row_base + ml;
    bool aok = arow < n;

    f32x4 acc[16];
#pragma unroll
    for (int t = 0; t < 16; t++) acc[t] = {0.f, 0.f, 0.f, 0.f};

    const __hip_bfloat16* As[2] = {A1, A2};
    const __hip_bfloat16* Ws[2] = {W1t, W2t};
#pragma unroll
    for (int pass = 0; pass < 2; pass++) {
        const __hip_bfloat16* A = As[pass];
        const __hip_bfloat16* Wt = Ws[pass];
        for (int k0 = 0; k0 < K; k0 += 32) {
            short8v afrag = {0, 0, 0, 0, 0, 0, 0, 0};
            if (aok)
                afrag = *(const short8v*)(A + (size_t)arow * K + k0 + quad * 8);
#pragma unroll
            for (int t = 0; t < 16; t++) {
                short8v bfrag = *(const short8v*)(Wt + (size_t)(t * 16 + ml) * K + k0 + quad * 8);
                acc[t] = __builtin_amdgcn_mfma_f32_16x16x32_bf16(afrag, bfrag, acc[t], 0, 0, 0);
            }
        }
    }

#pragma unroll
    for (int t = 0; t < 16; t++) {
        int c = t * 16 + ml;
        float sv = g[c] * rsqrtf(rv[c] + BN_EPS);
        float tv = (bl[c] - rm[c]) * sv + bb[c];
#pragma unroll
        for (int r = 0; r < 4; r++) {
            int row = row_base + quad * 4 + r;
            if (row < n) {
                float v = acc[t][r] * sv + tv;
                if (RELU) v = fmaxf(v, 0.f);
                if constexpr (sizeof(OutT) == 2)
                    out[(size_t)row * HID + c] = (OutT)__float2bfloat16(v);
                else
                    out[(size_t)row * HID + c] = (OutT)v;
            }
        }
    }
}

extern "C" void kernel_launch(void* const* d_in, const int* in_sizes, int n_in,
                              void* d_out, int out_size, void* d_ws, size_t ws_size,
                              hipStream_t stream) {
    const float* x = (const float*)d_in[0];
    const int* ei = (const int*)d_in[1];
    const float *Wl[3], *blv[3], *Wr[3], *g[3], *bb[3], *rm[3], *rv[3];
    for (int i = 0; i < 3; i++) {
        int b = 2 + i * 7;
        Wl[i]  = (const float*)d_in[b + 0];
        blv[i] = (const float*)d_in[b + 1];
        Wr[i]  = (const float*)d_in[b + 2];
        g[i]   = (const float*)d_in[b + 3];
        bb[i]  = (const float*)d_in[b + 4];
        rm[i]  = (const float*)d_in[b + 5];
        rv[i]  = (const float*)d_in[b + 6];
    }

    // scratch inside d_out (fully overwritten by the final GEMM):
    //   xb (bf16 x, 12.8 MB) at d_out+0 ; h0 (bf16, 25.6 MB) after it.
    char* ob = (char*)d_out;
    __hip_bfloat16* xb = (__hip_bfloat16*)ob;                           // 50000*128*2
    __hip_bfloat16* h0 = (__hip_bfloat16*)(ob + (size_t)NNODES * 128 * 2);

    char* w = (char*)d_ws;
    size_t off = 0;
    auto alloc = [&](size_t bytes) {
        void* p = w + off;
        off += (bytes + 255) & ~(size_t)255;
        return p;
    };
    int* rowptr = (int*)alloc((NNODES + 1) * sizeof(int));
    int* cursor = (int*)alloc(NNODES * sizeof(int));
    int* col    = (int*)alloc(NEDGES * sizeof(int));
    __hip_bfloat16* meanb = (__hip_bfloat16*)alloc((size_t)NNODES * HID * 2);
    __hip_bfloat16* h1    = (__hip_bfloat16*)alloc((size_t)NNODES * HID * 2);
    __hip_bfloat16* Wt[6];
    int Ks[6] = {128, 128, 256, 256, 256, 256};
    for (int i = 0; i < 6; i++) Wt[i] = (__hip_bfloat16*)alloc((size_t)Ks[i] * HID * 2);

    // CSR build
    k_zero<<<(NNODES + 255) / 256, 256, 0, stream>>>(cursor, NNODES);
    k_count<<<(NEDGES + 255) / 256, 256, 0, stream>>>(ei, cursor, NEDGES);
    k_scan<<<1, 1024, 0, stream>>>(cursor, rowptr, NNODES, NEDGES);
    k_fill<<<(NEDGES + 255) / 256, 256, 0, stream>>>(ei, cursor, col, NEDGES);

    // x -> bf16
    k_cast<<<(NNODES * 128 / 4 + 255) / 256, 256, 0, stream>>>(x, xb, NNODES * 128);

    // weight transposes: Wl0, Wr0, Wl1, Wr1, Wl2, Wr2
    const float* Wsrc[6] = {Wl[0], Wr[0], Wl[1], Wr[1], Wl[2], Wr[2]};
    for (int i = 0; i < 6; i++) {
        int total = Ks[i] * HID;
        k_transpose<<<(total + 255) / 256, 256, 0, stream>>>(Wsrc[i], Wt[i], Ks[i]);
    }

    int meanBlocks = (NNODES * 64 + 255) / 256;
    int gemmBlocks = (NNODES + 63) / 64;

    // layer 0 (K=128): mean over xb -> meanb ; h0 = relu(bn(meanb@Wl0 + xb@Wr0))
    k_mean<2><<<meanBlocks, 256, 0, stream>>>(xb, rowptr, col, meanb, NNODES);
    k_gemm<128, __hip_bfloat16, 1><<<gemmBlocks, 256, 0, stream>>>(meanb, xb, Wt[0], Wt[1],
        blv[0], g[0], bb[0], rm[0], rv[0], h0, NNODES);

    // layer 1 (K=256)
    k_mean<4><<<meanBlocks, 256, 0, stream>>>(h0, rowptr, col, meanb, NNODES);
    k_gemm<256, __hip_bfloat16, 1><<<gemmBlocks, 256, 0, stream>>>(meanb, h0, Wt[2], Wt[3],
        blv[1], g[1], bb[1], rm[1], rv[1], h1, NNODES);

    // layer 2 (K=256, no relu) -> f32 d_out (fully overwrites the scratch regions)
    k_mean<4><<<meanBlocks, 256, 0, stream>>>(h1, rowptr, col, meanb, NNODES);
    k_gemm<256, float, 0><<<gemmBlocks, 256, 0, stream>>>(meanb, h1, Wt[4], Wt[5],
        blv[2], g[2], bb[2], rm[2], rv[2], (float*)d_out, NNODES);
}

// Round 3
// 578.454 us; speedup vs baseline: 1.6045x; 1.6045x over previous
//
#include <hip/hip_runtime.h>
#include <hip/hip_bf16.h>

#define NNODES 50000
#define NEDGES 800000
#define HID 256
#define BN_EPS 1e-5f

typedef __attribute__((ext_vector_type(8))) short short8v;
typedef __attribute__((ext_vector_type(4))) float f32x4;

__device__ inline void load_lds16(const void* g, void* l) {
    __builtin_amdgcn_global_load_lds(
        (const __attribute__((address_space(1))) unsigned int*)g,
        (__attribute__((address_space(3))) unsigned int*)l, 16, 0, 0);
}

// ---------------- CSR build ----------------
__global__ void k_zero(int* p, int n) {
    int i = blockIdx.x * blockDim.x + threadIdx.x;
    if (i < n) p[i] = 0;
}

__global__ void k_count(const int* __restrict__ ei, int* __restrict__ cnt, int nE) {
    int e = blockIdx.x * blockDim.x + threadIdx.x;
    if (e < nE) atomicAdd(&cnt[ei[nE + e]], 1);   // dst = ei[E + e]
}

__global__ void k_scan(int* __restrict__ cursor, int* __restrict__ rowptr, int n, int nE) {
    __shared__ int sums[1024];
    int tid = threadIdx.x;
    int per = (n + 1023) >> 10;
    int start = tid * per;
    int end = start + per; if (end > n) end = n;
    int s = 0;
    for (int i = start; i < end; i++) s += cursor[i];
    sums[tid] = s;
    __syncthreads();
    for (int off = 1; off < 1024; off <<= 1) {
        int v = (tid >= off) ? sums[tid - off] : 0;
        __syncthreads();
        sums[tid] += v;
        __syncthreads();
    }
    int run = sums[tid] - s;   // exclusive prefix
    for (int i = start; i < end; i++) {
        int c = cursor[i];
        rowptr[i] = run;
        cursor[i] = run;
        run += c;
    }
    if (tid == 0) rowptr[n] = nE;
}

__global__ void k_fill(const int* __restrict__ ei, int* __restrict__ cursor,
                       int* __restrict__ col, int nE) {
    int e = blockIdx.x * blockDim.x + threadIdx.x;
    if (e < nE) {
        int p = atomicAdd(&cursor[ei[nE + e]], 1);
        col[p] = ei[e];   // src
    }
}

// ---------------- cast f32 -> bf16 ----------------
__global__ void k_cast(const float* __restrict__ in, __hip_bfloat16* __restrict__ out, int n) {
    int i = blockIdx.x * blockDim.x + threadIdx.x;
    int base = i * 4;
    if (base + 3 < n) {
        float4 v = *(const float4*)(in + base);
        out[base + 0] = __float2bfloat16(v.x);
        out[base + 1] = __float2bfloat16(v.y);
        out[base + 2] = __float2bfloat16(v.z);
        out[base + 3] = __float2bfloat16(v.w);
    } else {
        for (int j = base; j < n; j++) out[j] = __float2bfloat16(in[j]);
    }
}

// ---------------- weight transpose: W[K][256] f32 -> Wt[256][K] bf16 ----------------
__global__ void k_transpose(const float* __restrict__ W,
                            __hip_bfloat16* __restrict__ Wt, int K) {
    int i = blockIdx.x * blockDim.x + threadIdx.x;
    if (i < K * HID) {
        int k = i >> 8;        // /256
        int nn = i & 255;
        Wt[nn * K + k] = __float2bfloat16(W[i]);
    }
}

// ---------------- mean aggregation: one wave per node, 4x unrolled gather ----
template <int F>
__global__ void k_mean(const __hip_bfloat16* __restrict__ xin,
                       const int* __restrict__ rowptr, const int* __restrict__ col,
                       __hip_bfloat16* __restrict__ mean, int n) {
    int gw = (blockIdx.x * blockDim.x + threadIdx.x) >> 6;
    int lane = threadIdx.x & 63;
    if (gw >= n) return;
    int beg = rowptr[gw], end = rowptr[gw + 1];
    constexpr int D = F * 64;
    float acc[F];
#pragma unroll
    for (int j = 0; j < F; j++) acc[j] = 0.f;
    const unsigned int* base = (const unsigned int*)xin;
    int lo = (lane * F) >> 1;   // uint offset within row
    int p = beg;
    if constexpr (F == 4) {
        for (; p + 4 <= end; p += 4) {
            int s0 = col[p], s1 = col[p + 1], s2 = col[p + 2], s3 = col[p + 3];
            uint2 v0 = *(const uint2*)(base + (size_t)s0 * (D / 2) + lo);
            uint2 v1 = *(const uint2*)(base + (size_t)s1 * (D / 2) + lo);
            uint2 v2 = *(const uint2*)(base + (size_t)s2 * (D / 2) + lo);
            uint2 v3 = *(const uint2*)(base + (size_t)s3 * (D / 2) + lo);
            acc[0] += __uint_as_float(v0.x << 16) + __uint_as_float(v1.x << 16)
                    + __uint_as_float(v2.x << 16) + __uint_as_float(v3.x << 16);
            acc[1] += __uint_as_float(v0.x & 0xffff0000u) + __uint_as_float(v1.x & 0xffff0000u)
                    + __uint_as_float(v2.x & 0xffff0000u) + __uint_as_float(v3.x & 0xffff0000u);
            acc[2] += __uint_as_float(v0.y << 16) + __uint_as_float(v1.y << 16)
                    + __uint_as_float(v2.y << 16) + __uint_as_float(v3.y << 16);
            acc[3] += __uint_as_float(v0.y & 0xffff0000u) + __uint_as_float(v1.y & 0xffff0000u)
                    + __uint_as_float(v2.y & 0xffff0000u) + __uint_as_float(v3.y & 0xffff0000u);
        }
        for (; p < end; p++) {
            int s = col[p];
            uint2 v = *(const uint2*)(base + (size_t)s * (D / 2) + lo);
            acc[0] += __uint_as_float(v.x << 16);
            acc[1] += __uint_as_float(v.x & 0xffff0000u);
            acc[2] += __uint_as_float(v.y << 16);
            acc[3] += __uint_as_float(v.y & 0xffff0000u);
        }
    } else {
        for (; p + 4 <= end; p += 4) {
            int s0 = col[p], s1 = col[p + 1], s2 = col[p + 2], s3 = col[p + 3];
            unsigned int v0 = base[(size_t)s0 * (D / 2) + lo];
            unsigned int v1 = base[(size_t)s1 * (D / 2) + lo];
            unsigned int v2 = base[(size_t)s2 * (D / 2) + lo];
            unsigned int v3 = base[(size_t)s3 * (D / 2) + lo];
            acc[0] += __uint_as_float(v0 << 16) + __uint_as_float(v1 << 16)
                    + __uint_as_float(v2 << 16) + __uint_as_float(v3 << 16);
            acc[1] += __uint_as_float(v0 & 0xffff0000u) + __uint_as_float(v1 & 0xffff0000u)
                    + __uint_as_float(v2 & 0xffff0000u) + __uint_as_float(v3 & 0xffff0000u);
        }
        for (; p < end; p++) {
            unsigned int v = base[(size_t)col[p] * (D / 2) + lo];
            acc[0] += __uint_as_float(v << 16);
            acc[1] += __uint_as_float(v & 0xffff0000u);
        }
    }
    float inv = (end > beg) ? 1.f / (float)(end - beg) : 0.f;
#pragma unroll
    for (int j = 0; j < F; j++)
        mean[(size_t)gw * D + lane * F + j] = __float2bfloat16(acc[j] * inv);
}

// ---------------- fused GEMM + BN (+ReLU), LDS-staged 128x128 tile ----------
// out[n,256] = act( (A1@W1 + A2@W2 + bl - rm) * g*rsqrt(rv+eps) + b )
// A1,A2 bf16 [n,K]; W?t bf16 [256,K]; BN params f32; out f32 or bf16.
// grid: (ceil(n/128) * 2) blocks; blockIdx>>1 = row block, &1 = col block.
// block: 256 thr = 4 waves in 2x2; wave computes 64x64 via 4x4 MFMA tiles.
template <int K, typename OutT, int RELU>
__launch_bounds__(256)
__global__ void k_gemm(const __hip_bfloat16* __restrict__ A1,
                       const __hip_bfloat16* __restrict__ A2,
                       const __hip_bfloat16* __restrict__ W1t,
                       const __hip_bfloat16* __restrict__ W2t,
                       const float* __restrict__ bl,
                       const float* __restrict__ g,
                       const float* __restrict__ bb,
                       const float* __restrict__ rm,
                       const float* __restrict__ rv,
                       OutT* __restrict__ out, int n) {
    __shared__ __hip_bfloat16 As[128 * 32];   // [row][32k] row-major, 8 KB
    __shared__ __hip_bfloat16 Bs[128 * 32];   // [col][32k] row-major, 8 KB
    int tid = threadIdx.x;
    int lane = tid & 63;
    int w = tid >> 6;
    int quad = lane >> 4;
    int ml = lane & 15;
    int rowBase = (blockIdx.x >> 1) * 128;
    int colBase = (blockIdx.x & 1) * 128;
    int wr = w >> 1, wc = w & 1;              // wave 2x2 position

    f32x4 acc[4][4];
#pragma unroll
    for (int i = 0; i < 4; i++)
#pragma unroll
        for (int t = 0; t < 4; t++) acc[i][t] = {0.f, 0.f, 0.f, 0.f};

    int srow = tid >> 2;                      // 0..63 (staging row/col index)
    int sbyte = (tid & 3) * 16;               // byte offset within 64B k-row

    for (int s = 0; s < 2 * K; s += 32) {
        const __hip_bfloat16* A = (s < K) ? A1 : A2;
        const __hip_bfloat16* Wt = (s < K) ? W1t : W2t;
        int k0 = (s < K) ? s : (s - K);
        __syncthreads();   // previous iter's ds_reads done before overwrite
#pragma unroll
        for (int h = 0; h < 2; h++) {
            int r = srow + h * 64;
            int grow = rowBase + r; if (grow >= n) grow = n - 1;
            load_lds16((const char*)(A + (size_t)grow * K + k0) + sbyte,
                       (char*)As + r * 64 + sbyte);
        }
#pragma unroll
        for (int h = 0; h < 2; h++) {
            int c = srow + h * 64;
            load_lds16((const char*)(Wt + (size_t)(colBase + c) * K + k0) + sbyte,
                       (char*)Bs + c * 64 + sbyte);
        }
        __syncthreads();   // staging visible to all waves

        short8v af[4], bf[4];
#pragma unroll
        for (int i = 0; i < 4; i++)
            af[i] = *(const short8v*)(As + (wr * 64 + i * 16 + ml) * 32 + quad * 8);
#pragma unroll
        for (int t = 0; t < 4; t++)
            bf[t] = *(const short8v*)(Bs + (wc * 64 + t * 16 + ml) * 32 + quad * 8);
#pragma unroll
        for (int i = 0; i < 4; i++)
#pragma unroll
            for (int t = 0; t < 4; t++)
                acc[i][t] = __builtin_amdgcn_mfma_f32_16x16x32_bf16(af[i], bf[t], acc[i][t], 0, 0, 0);
    }

    // epilogue: C/D layout col=lane&15, row=quad*4+reg
#pragma unroll
    for (int t = 0; t < 4; t++) {
        int c = colBase + wc * 64 + t * 16 + ml;
        float sv = g[c] * rsqrtf(rv[c] + BN_EPS);
        float tv = (bl[c] - rm[c]) * sv + bb[c];
#pragma unroll
        for (int i = 0; i < 4; i++) {
            int row0 = rowBase + wr * 64 + i * 16 + quad * 4;
#pragma unroll
            for (int r = 0; r < 4; r++) {
                int row = row0 + r;
                if (row < n) {
                    float v = acc[i][t][r] * sv + tv;
                    if (RELU) v = fmaxf(v, 0.f);
                    if constexpr (sizeof(OutT) == 2)
                        out[(size_t)row * HID + c] = (OutT)__float2bfloat16(v);
                    else
                        out[(size_t)row * HID + c] = (OutT)v;
                }
            }
        }
    }
}

extern "C" void kernel_launch(void* const* d_in, const int* in_sizes, int n_in,
                              void* d_out, int out_size, void* d_ws, size_t ws_size,
                              hipStream_t stream) {
    const float* x = (const float*)d_in[0];
    const int* ei = (const int*)d_in[1];
    const float *Wl[3], *blv[3], *Wr[3], *g[3], *bb[3], *rm[3], *rv[3];
    for (int i = 0; i < 3; i++) {
        int b = 2 + i * 7;
        Wl[i]  = (const float*)d_in[b + 0];
        blv[i] = (const float*)d_in[b + 1];
        Wr[i]  = (const float*)d_in[b + 2];
        g[i]   = (const float*)d_in[b + 3];
        bb[i]  = (const float*)d_in[b + 4];
        rm[i]  = (const float*)d_in[b + 5];
        rv[i]  = (const float*)d_in[b + 6];
    }

    // scratch inside d_out (fully overwritten by the final GEMM):
    char* ob = (char*)d_out;
    __hip_bfloat16* xb = (__hip_bfloat16*)ob;                            // 12.8 MB
    __hip_bfloat16* h0 = (__hip_bfloat16*)(ob + (size_t)NNODES * 128 * 2); // 25.6 MB

    char* w = (char*)d_ws;
    size_t off = 0;
    auto alloc = [&](size_t bytes) {
        void* p = w + off;
        off += (bytes + 255) & ~(size_t)255;
        return p;
    };
    int* rowptr = (int*)alloc((NNODES + 1) * sizeof(int));
    int* cursor = (int*)alloc(NNODES * sizeof(int));
    int* col    = (int*)alloc(NEDGES * sizeof(int));
    __hip_bfloat16* meanb = (__hip_bfloat16*)alloc((size_t)NNODES * HID * 2);
    __hip_bfloat16* h1    = (__hip_bfloat16*)alloc((size_t)NNODES * HID * 2);
    __hip_bfloat16* Wt[6];
    int Ks[6] = {128, 128, 256, 256, 256, 256};
    for (int i = 0; i < 6; i++) Wt[i] = (__hip_bfloat16*)alloc((size_t)Ks[i] * HID * 2);

    // CSR build
    k_zero<<<(NNODES + 255) / 256, 256, 0, stream>>>(cursor, NNODES);
    k_count<<<(NEDGES + 255) / 256, 256, 0, stream>>>(ei, cursor, NEDGES);
    k_scan<<<1, 1024, 0, stream>>>(cursor, rowptr, NNODES, NEDGES);
    k_fill<<<(NEDGES + 255) / 256, 256, 0, stream>>>(ei, cursor, col, NEDGES);

    // x -> bf16
    k_cast<<<(NNODES * 128 / 4 + 255) / 256, 256, 0, stream>>>(x, xb, NNODES * 128);

    // weight transposes: Wl0, Wr0, Wl1, Wr1, Wl2, Wr2
    const float* Wsrc[6] = {Wl[0], Wr[0], Wl[1], Wr[1], Wl[2], Wr[2]};
    for (int i = 0; i < 6; i++) {
        int total = Ks[i] * HID;
        k_transpose<<<(total + 255) / 256, 256, 0, stream>>>(Wsrc[i], Wt[i], Ks[i]);
    }

    int meanBlocks = (NNODES * 64 + 255) / 256;
    int gemmBlocks = ((NNODES + 127) / 128) * 2;

    // layer 0 (K=128)
    k_mean<2><<<meanBlocks, 256, 0, stream>>>(xb, rowptr, col, meanb, NNODES);
    k_gemm<128, __hip_bfloat16, 1><<<gemmBlocks, 256, 0, stream>>>(meanb, xb, Wt[0], Wt[1],
        blv[0], g[0], bb[0], rm[0], rv[0], h0, NNODES);

    // layer 1 (K=256)
    k_mean<4><<<meanBlocks, 256, 0, stream>>>(h0, rowptr, col, meanb, NNODES);
    k_gemm<256, __hip_bfloat16, 1><<<gemmBlocks, 256, 0, stream>>>(meanb, h0, Wt[2], Wt[3],
        blv[1], g[1], bb[1], rm[1], rv[1], h1, NNODES);

    // layer 2 (K=256, no relu) -> f32 d_out (fully overwrites scratch regions)
    k_mean<4><<<meanBlocks, 256, 0, stream>>>(h1, rowptr, col, meanb, NNODES);
    k_gemm<256, float, 0><<<gemmBlocks, 256, 0, stream>>>(meanb, h1, Wt[4], Wt[5],
        blv[2], g[2], bb[2], rm[2], rv[2], (float*)d_out, NNODES);
}

// Round 4
// 468.685 us; speedup vs baseline: 1.9803x; 1.2342x over previous
//
#include <hip/hip_runtime.h>
#include <hip/hip_bf16.h>

#define NNODES 50000
#define NEDGES 800000
#define HID 256
#define BN_EPS 1e-5f
#define SCAN_B ((NNODES + 255) / 256)   // 196 blocks

typedef __attribute__((ext_vector_type(8))) short short8v;
typedef __attribute__((ext_vector_type(4))) float f32x4;

__device__ inline void load_lds16(const void* g, void* l) {
    __builtin_amdgcn_global_load_lds(
        (const __attribute__((address_space(1))) unsigned int*)g,
        (__attribute__((address_space(3))) unsigned int*)l, 16, 0, 0);
}

// ---------------- CSR build ----------------
__global__ void k_zero(int* p, int n) {
    int i = blockIdx.x * blockDim.x + threadIdx.x;
    if (i < n) p[i] = 0;
}

__global__ void k_count(const int* __restrict__ ei, int* __restrict__ cnt, int nE) {
    int e = blockIdx.x * blockDim.x + threadIdx.x;
    if (e < nE) atomicAdd(&cnt[ei[nE + e]], 1);   // dst = ei[E + e]
}

// phase 1: per-block exclusive scan of 256 counts -> loc, block total -> bsum
__global__ void k_bsum(const int* __restrict__ cnt, int* __restrict__ loc,
                       int* __restrict__ bsum, int n) {
    __shared__ int sh[256];
    int tid = threadIdx.x;
    int i = blockIdx.x * 256 + tid;
    int v = (i < n) ? cnt[i] : 0;
    sh[tid] = v;
    __syncthreads();
    for (int off = 1; off < 256; off <<= 1) {
        int t = (tid >= off) ? sh[tid - off] : 0;
        __syncthreads();
        sh[tid] += t;
        __syncthreads();
    }
    if (i < n) loc[i] = sh[tid] - v;          // exclusive
    if (tid == 255) bsum[blockIdx.x] = sh[255];
}

// phase 2: one block scans the block sums (nb <= 256) in-place -> exclusive
__global__ void k_bscan(int* __restrict__ bsum, int nb) {
    __shared__ int sh[256];
    int tid = threadIdx.x;
    int v = (tid < nb) ? bsum[tid] : 0;
    sh[tid] = v;
    __syncthreads();
    for (int off = 1; off < 256; off <<= 1) {
        int t = (tid >= off) ? sh[tid - off] : 0;
        __syncthreads();
        sh[tid] += t;
        __syncthreads();
    }
    if (tid < nb) bsum[tid] = sh[tid] - v;    // exclusive
}

// phase 3: global offsets -> rowptr & cursor
__global__ void k_addoff(const int* __restrict__ loc, const int* __restrict__ bsum,
                         int* __restrict__ rowptr, int* __restrict__ cursor,
                         int n, int nE) {
    int i = blockIdx.x * 256 + threadIdx.x;
    if (i < n) {
        int v = loc[i] + bsum[blockIdx.x];
        rowptr[i] = v;
        cursor[i] = v;
    }
    if (i == 0) rowptr[n] = nE;
}

__global__ void k_fill(const int* __restrict__ ei, int* __restrict__ cursor,
                       int* __restrict__ col, int nE) {
    int e = blockIdx.x * blockDim.x + threadIdx.x;
    if (e < nE) {
        int p = atomicAdd(&cursor[ei[nE + e]], 1);
        col[p] = ei[e];   // src
    }
}

// ---------------- cast f32 -> bf16 ----------------
__global__ void k_cast(const float* __restrict__ in, __hip_bfloat16* __restrict__ out, int n) {
    int i = blockIdx.x * blockDim.x + threadIdx.x;
    int base = i * 4;
    if (base + 3 < n) {
        float4 v = *(const float4*)(in + base);
        out[base + 0] = __float2bfloat16(v.x);
        out[base + 1] = __float2bfloat16(v.y);
        out[base + 2] = __float2bfloat16(v.z);
        out[base + 3] = __float2bfloat16(v.w);
    } else {
        for (int j = base; j < n; j++) out[j] = __float2bfloat16(in[j]);
    }
}

// ---------------- fused weight transpose: 6x W[K][256] f32 -> Wt[256][K] bf16 ----
__global__ void k_transpose6(const float* __restrict__ s0, const float* __restrict__ s1,
                             const float* __restrict__ s2, const float* __restrict__ s3,
                             const float* __restrict__ s4, const float* __restrict__ s5,
                             __hip_bfloat16* __restrict__ d0, __hip_bfloat16* __restrict__ d1,
                             __hip_bfloat16* __restrict__ d2, __hip_bfloat16* __restrict__ d3,
                             __hip_bfloat16* __restrict__ d4, __hip_bfloat16* __restrict__ d5) {
    int f = blockIdx.x * blockDim.x + threadIdx.x;   // 0 .. 327679
    const float* src; __hip_bfloat16* dst; int K; int i;
    if (f < 65536) {                                  // two 128x256 weights
        K = 128;
        if (f < 32768) { src = s0; dst = d0; i = f; }
        else           { src = s1; dst = d1; i = f - 32768; }
    } else {                                          // four 256x256 weights
        K = 256;
        int r = f - 65536;
        int wsel = r >> 16;                           // /65536
        i = r & 65535;
        src = (wsel == 0) ? s2 : (wsel == 1) ? s3 : (wsel == 2) ? s4 : s5;
        dst = (wsel == 0) ? d2 : (wsel == 1) ? d3 : (wsel == 2) ? d4 : d5;
    }
    int k = i >> 8;
    int nn = i & 255;
    dst[nn * K + k] = __float2bfloat16(src[i]);
}

// ---------------- mean aggregation: one wave per node, 4x unrolled gather ----
template <int F>
__global__ void k_mean(const __hip_bfloat16* __restrict__ xin,
                       const int* __restrict__ rowptr, const int* __restrict__ col,
                       __hip_bfloat16* __restrict__ mean, int n) {
    int gw = (blockIdx.x * blockDim.x + threadIdx.x) >> 6;
    int lane = threadIdx.x & 63;
    if (gw >= n) return;
    int beg = rowptr[gw], end = rowptr[gw + 1];
    constexpr int D = F * 64;
    float acc[F];
#pragma unroll
    for (int j = 0; j < F; j++) acc[j] = 0.f;
    const unsigned int* base = (const unsigned int*)xin;
    int lo = (lane * F) >> 1;   // uint offset within row
    int p = beg;
    if constexpr (F == 4) {
        for (; p + 4 <= end; p += 4) {
            int s0 = col[p], s1 = col[p + 1], s2 = col[p + 2], s3 = col[p + 3];
            uint2 v0 = *(const uint2*)(base + (size_t)s0 * (D / 2) + lo);
            uint2 v1 = *(const uint2*)(base + (size_t)s1 * (D / 2) + lo);
            uint2 v2 = *(const uint2*)(base + (size_t)s2 * (D / 2) + lo);
            uint2 v3 = *(const uint2*)(base + (size_t)s3 * (D / 2) + lo);
            acc[0] += __uint_as_float(v0.x << 16) + __uint_as_float(v1.x << 16)
                    + __uint_as_float(v2.x << 16) + __uint_as_float(v3.x << 16);
            acc[1] += __uint_as_float(v0.x & 0xffff0000u) + __uint_as_float(v1.x & 0xffff0000u)
                    + __uint_as_float(v2.x & 0xffff0000u) + __uint_as_float(v3.x & 0xffff0000u);
            acc[2] += __uint_as_float(v0.y << 16) + __uint_as_float(v1.y << 16)
                    + __uint_as_float(v2.y << 16) + __uint_as_float(v3.y << 16);
            acc[3] += __uint_as_float(v0.y & 0xffff0000u) + __uint_as_float(v1.y & 0xffff0000u)
                    + __uint_as_float(v2.y & 0xffff0000u) + __uint_as_float(v3.y & 0xffff0000u);
        }
        for (; p < end; p++) {
            int s = col[p];
            uint2 v = *(const uint2*)(base + (size_t)s * (D / 2) + lo);
            acc[0] += __uint_as_float(v.x << 16);
            acc[1] += __uint_as_float(v.x & 0xffff0000u);
            acc[2] += __uint_as_float(v.y << 16);
            acc[3] += __uint_as_float(v.y & 0xffff0000u);
        }
    } else {
        for (; p + 4 <= end; p += 4) {
            int s0 = col[p], s1 = col[p + 1], s2 = col[p + 2], s3 = col[p + 3];
            unsigned int v0 = base[(size_t)s0 * (D / 2) + lo];
            unsigned int v1 = base[(size_t)s1 * (D / 2) + lo];
            unsigned int v2 = base[(size_t)s2 * (D / 2) + lo];
            unsigned int v3 = base[(size_t)s3 * (D / 2) + lo];
            acc[0] += __uint_as_float(v0 << 16) + __uint_as_float(v1 << 16)
                    + __uint_as_float(v2 << 16) + __uint_as_float(v3 << 16);
            acc[1] += __uint_as_float(v0 & 0xffff0000u) + __uint_as_float(v1 & 0xffff0000u)
                    + __uint_as_float(v2 & 0xffff0000u) + __uint_as_float(v3 & 0xffff0000u);
        }
        for (; p < end; p++) {
            unsigned int v = base[(size_t)col[p] * (D / 2) + lo];
            acc[0] += __uint_as_float(v << 16);
            acc[1] += __uint_as_float(v & 0xffff0000u);
        }
    }
    float inv = (end > beg) ? 1.f / (float)(end - beg) : 0.f;
#pragma unroll
    for (int j = 0; j < F; j++)
        mean[(size_t)gw * D + lane * F + j] = __float2bfloat16(acc[j] * inv);
}

// ---------------- fused GEMM + BN (+ReLU), LDS-staged 128x128 tile ----------
template <int K, typename OutT, int RELU>
__launch_bounds__(256)
__global__ void k_gemm(const __hip_bfloat16* __restrict__ A1,
                       const __hip_bfloat16* __restrict__ A2,
                       const __hip_bfloat16* __restrict__ W1t,
                       const __hip_bfloat16* __restrict__ W2t,
                       const float* __restrict__ bl,
                       const float* __restrict__ g,
                       const float* __restrict__ bb,
                       const float* __restrict__ rm,
                       const float* __restrict__ rv,
                       OutT* __restrict__ out, int n) {
    __shared__ __hip_bfloat16 As[128 * 32];   // 8 KB
    __shared__ __hip_bfloat16 Bs[128 * 32];   // 8 KB
    int tid = threadIdx.x;
    int lane = tid & 63;
    int w = tid >> 6;
    int quad = lane >> 4;
    int ml = lane & 15;
    int rowBase = (blockIdx.x >> 1) * 128;
    int colBase = (blockIdx.x & 1) * 128;
    int wr = w >> 1, wc = w & 1;

    f32x4 acc[4][4];
#pragma unroll
    for (int i = 0; i < 4; i++)
#pragma unroll
        for (int t = 0; t < 4; t++) acc[i][t] = {0.f, 0.f, 0.f, 0.f};

    int srow = tid >> 2;
    int sbyte = (tid & 3) * 16;

    for (int s = 0; s < 2 * K; s += 32) {
        const __hip_bfloat16* A = (s < K) ? A1 : A2;
        const __hip_bfloat16* Wt = (s < K) ? W1t : W2t;
        int k0 = (s < K) ? s : (s - K);
        __syncthreads();
#pragma unroll
        for (int h = 0; h < 2; h++) {
            int r = srow + h * 64;
            int grow = rowBase + r; if (grow >= n) grow = n - 1;
            load_lds16((const char*)(A + (size_t)grow * K + k0) + sbyte,
                       (char*)As + r * 64 + sbyte);
        }
#pragma unroll
        for (int h = 0; h < 2; h++) {
            int c = srow + h * 64;
            load_lds16((const char*)(Wt + (size_t)(colBase + c) * K + k0) + sbyte,
                       (char*)Bs + c * 64 + sbyte);
        }
        __syncthreads();

        short8v af[4], bf[4];
#pragma unroll
        for (int i = 0; i < 4; i++)
            af[i] = *(const short8v*)(As + (wr * 64 + i * 16 + ml) * 32 + quad * 8);
#pragma unroll
        for (int t = 0; t < 4; t++)
            bf[t] = *(const short8v*)(Bs + (wc * 64 + t * 16 + ml) * 32 + quad * 8);
#pragma unroll
        for (int i = 0; i < 4; i++)
#pragma unroll
            for (int t = 0; t < 4; t++)
                acc[i][t] = __builtin_amdgcn_mfma_f32_16x16x32_bf16(af[i], bf[t], acc[i][t], 0, 0, 0);
    }

#pragma unroll
    for (int t = 0; t < 4; t++) {
        int c = colBase + wc * 64 + t * 16 + ml;
        float sv = g[c] * rsqrtf(rv[c] + BN_EPS);
        float tv = (bl[c] - rm[c]) * sv + bb[c];
#pragma unroll
        for (int i = 0; i < 4; i++) {
            int row0 = rowBase + wr * 64 + i * 16 + quad * 4;
#pragma unroll
            for (int r = 0; r < 4; r++) {
                int row = row0 + r;
                if (row < n) {
                    float v = acc[i][t][r] * sv + tv;
                    if (RELU) v = fmaxf(v, 0.f);
                    if constexpr (sizeof(OutT) == 2)
                        out[(size_t)row * HID + c] = (OutT)__float2bfloat16(v);
                    else
                        out[(size_t)row * HID + c] = (OutT)v;
                }
            }
        }
    }
}

extern "C" void kernel_launch(void* const* d_in, const int* in_sizes, int n_in,
                              void* d_out, int out_size, void* d_ws, size_t ws_size,
                              hipStream_t stream) {
    const float* x = (const float*)d_in[0];
    const int* ei = (const int*)d_in[1];
    const float *Wl[3], *blv[3], *Wr[3], *g[3], *bb[3], *rm[3], *rv[3];
    for (int i = 0; i < 3; i++) {
        int b = 2 + i * 7;
        Wl[i]  = (const float*)d_in[b + 0];
        blv[i] = (const float*)d_in[b + 1];
        Wr[i]  = (const float*)d_in[b + 2];
        g[i]   = (const float*)d_in[b + 3];
        bb[i]  = (const float*)d_in[b + 4];
        rm[i]  = (const float*)d_in[b + 5];
        rv[i]  = (const float*)d_in[b + 6];
    }

    // scratch inside d_out (fully overwritten by the final GEMM):
    char* ob = (char*)d_out;
    __hip_bfloat16* xb = (__hip_bfloat16*)ob;                              // 12.8 MB
    __hip_bfloat16* h0 = (__hip_bfloat16*)(ob + (size_t)NNODES * 128 * 2); // 25.6 MB

    char* w = (char*)d_ws;
    size_t off = 0;
    auto alloc = [&](size_t bytes) {
        void* p = w + off;
        off += (bytes + 255) & ~(size_t)255;
        return p;
    };
    int* rowptr = (int*)alloc((NNODES + 1) * sizeof(int));
    int* cursor = (int*)alloc(NNODES * sizeof(int));
    int* cnt    = (int*)alloc(NNODES * sizeof(int));
    int* loc    = (int*)alloc(NNODES * sizeof(int));
    int* bsum   = (int*)alloc(SCAN_B * sizeof(int));
    int* col    = (int*)alloc(NEDGES * sizeof(int));
    __hip_bfloat16* meanb = (__hip_bfloat16*)alloc((size_t)NNODES * HID * 2);
    __hip_bfloat16* h1    = (__hip_bfloat16*)alloc((size_t)NNODES * HID * 2);
    __hip_bfloat16* Wt[6];
    int Ks[6] = {128, 128, 256, 256, 256, 256};
    for (int i = 0; i < 6; i++) Wt[i] = (__hip_bfloat16*)alloc((size_t)Ks[i] * HID * 2);

    // CSR build (multi-block scan)
    k_zero<<<SCAN_B, 256, 0, stream>>>(cnt, NNODES);
    k_count<<<(NEDGES + 255) / 256, 256, 0, stream>>>(ei, cnt, NEDGES);
    k_bsum<<<SCAN_B, 256, 0, stream>>>(cnt, loc, bsum, NNODES);
    k_bscan<<<1, 256, 0, stream>>>(bsum, SCAN_B);
    k_addoff<<<SCAN_B, 256, 0, stream>>>(loc, bsum, rowptr, cursor, NNODES, NEDGES);
    k_fill<<<(NEDGES + 255) / 256, 256, 0, stream>>>(ei, cursor, col, NEDGES);

    // x -> bf16
    k_cast<<<(NNODES * 128 / 4 + 255) / 256, 256, 0, stream>>>(x, xb, NNODES * 128);

    // fused weight transposes (Wl0, Wr0, Wl1, Wr1, Wl2, Wr2): 327680 elements
    k_transpose6<<<(327680 + 255) / 256, 256, 0, stream>>>(
        Wl[0], Wr[0], Wl[1], Wr[1], Wl[2], Wr[2],
        Wt[0], Wt[1], Wt[2], Wt[3], Wt[4], Wt[5]);

    int meanBlocks = (NNODES * 64 + 255) / 256;
    int gemmBlocks = ((NNODES + 127) / 128) * 2;

    // layer 0 (K=128)
    k_mean<2><<<meanBlocks, 256, 0, stream>>>(xb, rowptr, col, meanb, NNODES);
    k_gemm<128, __hip_bfloat16, 1><<<gemmBlocks, 256, 0, stream>>>(meanb, xb, Wt[0], Wt[1],
        blv[0], g[0], bb[0], rm[0], rv[0], h0, NNODES);

    // layer 1 (K=256)
    k_mean<4><<<meanBlocks, 256, 0, stream>>>(h0, rowptr, col, meanb, NNODES);
    k_gemm<256, __hip_bfloat16, 1><<<gemmBlocks, 256, 0, stream>>>(meanb, h0, Wt[2], Wt[3],
        blv[1], g[1], bb[1], rm[1], rv[1], h1, NNODES);

    // layer 2 (K=256, no relu) -> f32 d_out
    k_mean<4><<<meanBlocks, 256, 0, stream>>>(h1, rowptr, col, meanb, NNODES);
    k_gemm<256, float, 0><<<gemmBlocks, 256, 0, stream>>>(meanb, h1, Wt[4], Wt[5],
        blv[2], g[2], bb[2], rm[2], rv[2], (float*)d_out, NNODES);
}

// Round 5
// 428.082 us; speedup vs baseline: 2.1682x; 1.0948x over previous
//
#include <hip/hip_runtime.h>
#include <hip/hip_bf16.h>

#define NNODES 50000
#define NEDGES 800000
#define HID 256
#define BN_EPS 1e-5f
#define SCAN_B ((NNODES + 255) / 256)   // 196 blocks

typedef __attribute__((ext_vector_type(8))) short short8v;
typedef __attribute__((ext_vector_type(4))) float f32x4;

__device__ inline void load_lds16(const void* g, void* l) {
    __builtin_amdgcn_global_load_lds(
        (const __attribute__((address_space(1))) unsigned int*)g,
        (__attribute__((address_space(3))) unsigned int*)l, 16, 0, 0);
}

// ---------------- CSR build ----------------
__global__ void k_zero(int* p, int n) {
    int i = blockIdx.x * blockDim.x + threadIdx.x;
    if (i < n) p[i] = 0;
}

// count AND rank in a single atomic pass
__global__ void k_countrank(const int* __restrict__ ei, int* __restrict__ cnt,
                            int* __restrict__ rank, int nE) {
    int e = blockIdx.x * blockDim.x + threadIdx.x;
    if (e < nE) rank[e] = atomicAdd(&cnt[ei[nE + e]], 1);
}

// phase 1: per-block exclusive scan of 256 counts -> loc, block total -> bsum
__global__ void k_bsum(const int* __restrict__ cnt, int* __restrict__ loc,
                       int* __restrict__ bsum, int n) {
    __shared__ int sh[256];
    int tid = threadIdx.x;
    int i = blockIdx.x * 256 + tid;
    int v = (i < n) ? cnt[i] : 0;
    sh[tid] = v;
    __syncthreads();
    for (int off = 1; off < 256; off <<= 1) {
        int t = (tid >= off) ? sh[tid - off] : 0;
        __syncthreads();
        sh[tid] += t;
        __syncthreads();
    }
    if (i < n) loc[i] = sh[tid] - v;          // exclusive
    if (tid == 255) bsum[blockIdx.x] = sh[255];
}

// phase 2: one block scans the block sums (nb <= 256) in-place -> exclusive
__global__ void k_bscan(int* __restrict__ bsum, int nb) {
    __shared__ int sh[256];
    int tid = threadIdx.x;
    int v = (tid < nb) ? bsum[tid] : 0;
    sh[tid] = v;
    __syncthreads();
    for (int off = 1; off < 256; off <<= 1) {
        int t = (tid >= off) ? sh[tid - off] : 0;
        __syncthreads();
        sh[tid] += t;
        __syncthreads();
    }
    if (tid < nb) bsum[tid] = sh[tid] - v;    // exclusive
}

// phase 3: global offsets -> rowptr
__global__ void k_addoff(const int* __restrict__ loc, const int* __restrict__ bsum,
                         int* __restrict__ rowptr, int n, int nE) {
    int i = blockIdx.x * 256 + threadIdx.x;
    if (i < n) rowptr[i] = loc[i] + bsum[blockIdx.x];
    if (i == 0) rowptr[n] = nE;
}

// pure scatter fill (no atomics)
__global__ void k_fill2(const int* __restrict__ ei, const int* __restrict__ rowptr,
                        const int* __restrict__ rank, int* __restrict__ col, int nE) {
    int e = blockIdx.x * blockDim.x + threadIdx.x;
    if (e < nE) col[rowptr[ei[nE + e]] + rank[e]] = ei[e];
}

// ---------------- cast f32 -> bf16 ----------------
__global__ void k_cast(const float* __restrict__ in, __hip_bfloat16* __restrict__ out, int n) {
    int i = blockIdx.x * blockDim.x + threadIdx.x;
    int base = i * 4;
    if (base + 3 < n) {
        float4 v = *(const float4*)(in + base);
        out[base + 0] = __float2bfloat16(v.x);
        out[base + 1] = __float2bfloat16(v.y);
        out[base + 2] = __float2bfloat16(v.z);
        out[base + 3] = __float2bfloat16(v.w);
    } else {
        for (int j = base; j < n; j++) out[j] = __float2bfloat16(in[j]);
    }
}

// ---------------- fused weight transpose: 6x W[K][256] f32 -> Wt[256][K] bf16 ----
__global__ void k_transpose6(const float* __restrict__ s0, const float* __restrict__ s1,
                             const float* __restrict__ s2, const float* __restrict__ s3,
                             const float* __restrict__ s4, const float* __restrict__ s5,
                             __hip_bfloat16* __restrict__ d0, __hip_bfloat16* __restrict__ d1,
                             __hip_bfloat16* __restrict__ d2, __hip_bfloat16* __restrict__ d3,
                             __hip_bfloat16* __restrict__ d4, __hip_bfloat16* __restrict__ d5) {
    int f = blockIdx.x * blockDim.x + threadIdx.x;   // 0 .. 327679
    const float* src; __hip_bfloat16* dst; int K; int i;
    if (f < 65536) {
        K = 128;
        if (f < 32768) { src = s0; dst = d0; i = f; }
        else           { src = s1; dst = d1; i = f - 32768; }
    } else {
        K = 256;
        int r = f - 65536;
        int wsel = r >> 16;
        i = r & 65535;
        src = (wsel == 0) ? s2 : (wsel == 1) ? s3 : (wsel == 2) ? s4 : s5;
        dst = (wsel == 0) ? d2 : (wsel == 1) ? d3 : (wsel == 2) ? d4 : d5;
    }
    int k = i >> 8;
    int nn = i & 255;
    dst[nn * K + k] = __float2bfloat16(src[i]);
}

// ---------------- mean aggregation: wave per node, 16B/lane gathers ----------
// D bf16 feats/row. CPL = D/8 lanes cover one row (16B each); R = 64/CPL rows
// per wave iteration; 2x unrolled -> 2 outstanding dwordx4 per lane.
template <int D>
__global__ void k_mean(const __hip_bfloat16* __restrict__ xin,
                       const int* __restrict__ rowptr, const int* __restrict__ col,
                       __hip_bfloat16* __restrict__ mean, int n) {
    constexpr int CPL = D / 8;      // lanes per row
    constexpr int R = 64 / CPL;     // neighbors per wave sub-step
    int gw = (blockIdx.x * blockDim.x + threadIdx.x) >> 6;
    int lane = threadIdx.x & 63;
    if (gw >= n) return;
    int beg = rowptr[gw], end = rowptr[gw + 1];
    int sub = lane / CPL;           // which neighbor slot
    int fpos = lane % CPL;          // 16B chunk within row
    const uint4* base = (const uint4*)xin;   // CPL uint4 per row

    float acc[8];
#pragma unroll
    for (int j = 0; j < 8; j++) acc[j] = 0.f;

    for (int p0 = beg; p0 < end; p0 += 2 * R) {
        int p1 = p0 + sub;
        int p2 = p0 + R + sub;
        uint4 v1 = {0u, 0u, 0u, 0u}, v2 = {0u, 0u, 0u, 0u};
        if (p1 < end) v1 = base[(size_t)col[p1] * CPL + fpos];
        if (p2 < end) v2 = base[(size_t)col[p2] * CPL + fpos];
        const unsigned int u1[4] = {v1.x, v1.y, v1.z, v1.w};
        const unsigned int u2[4] = {v2.x, v2.y, v2.z, v2.w};
#pragma unroll
        for (int j = 0; j < 4; j++) {
            acc[2 * j]     += __uint_as_float(u1[j] << 16) + __uint_as_float(u2[j] << 16);
            acc[2 * j + 1] += __uint_as_float(u1[j] & 0xffff0000u) + __uint_as_float(u2[j] & 0xffff0000u);
        }
    }

    // reduce across sub groups (lanes sharing fpos)
    if constexpr (R >= 2) {
#pragma unroll
        for (int j = 0; j < 8; j++) acc[j] += __shfl_xor(acc[j], 32, 64);
    }
    if constexpr (R == 4) {
#pragma unroll
        for (int j = 0; j < 8; j++) acc[j] += __shfl_xor(acc[j], 16, 64);
    }

    if (sub == 0) {
        float inv = (end > beg) ? 1.f / (float)(end - beg) : 0.f;
        union { uint4 v; unsigned short s[8]; } o;
#pragma unroll
        for (int j = 0; j < 8; j++)
            o.s[j] = __bfloat16_as_ushort(__float2bfloat16(acc[j] * inv));
        *(uint4*)(mean + (size_t)gw * D + fpos * 8) = o.v;
    }
}

// ---------------- fused GEMM + BN (+ReLU), LDS-staged 128x128 tile ----------
template <int K, typename OutT, int RELU>
__launch_bounds__(256)
__global__ void k_gemm(const __hip_bfloat16* __restrict__ A1,
                       const __hip_bfloat16* __restrict__ A2,
                       const __hip_bfloat16* __restrict__ W1t,
                       const __hip_bfloat16* __restrict__ W2t,
                       const float* __restrict__ bl,
                       const float* __restrict__ g,
                       const float* __restrict__ bb,
                       const float* __restrict__ rm,
                       const float* __restrict__ rv,
                       OutT* __restrict__ out, int n) {
    __shared__ __hip_bfloat16 As[128 * 32];   // 8 KB
    __shared__ __hip_bfloat16 Bs[128 * 32];   // 8 KB
    int tid = threadIdx.x;
    int lane = tid & 63;
    int w = tid >> 6;
    int quad = lane >> 4;
    int ml = lane & 15;
    int rowBase = (blockIdx.x >> 1) * 128;
    int colBase = (blockIdx.x & 1) * 128;
    int wr = w >> 1, wc = w & 1;

    f32x4 acc[4][4];
#pragma unroll
    for (int i = 0; i < 4; i++)
#pragma unroll
        for (int t = 0; t < 4; t++) acc[i][t] = {0.f, 0.f, 0.f, 0.f};

    int srow = tid >> 2;
    int sbyte = (tid & 3) * 16;

    for (int s = 0; s < 2 * K; s += 32) {
        const __hip_bfloat16* A = (s < K) ? A1 : A2;
        const __hip_bfloat16* Wt = (s < K) ? W1t : W2t;
        int k0 = (s < K) ? s : (s - K);
        __syncthreads();
#pragma unroll
        for (int h = 0; h < 2; h++) {
            int r = srow + h * 64;
            int grow = rowBase + r; if (grow >= n) grow = n - 1;
            load_lds16((const char*)(A + (size_t)grow * K + k0) + sbyte,
                       (char*)As + r * 64 + sbyte);
        }
#pragma unroll
        for (int h = 0; h < 2; h++) {
            int c = srow + h * 64;
            load_lds16((const char*)(Wt + (size_t)(colBase + c) * K + k0) + sbyte,
                       (char*)Bs + c * 64 + sbyte);
        }
        __syncthreads();

        short8v af[4], bf[4];
#pragma unroll
        for (int i = 0; i < 4; i++)
            af[i] = *(const short8v*)(As + (wr * 64 + i * 16 + ml) * 32 + quad * 8);
#pragma unroll
        for (int t = 0; t < 4; t++)
            bf[t] = *(const short8v*)(Bs + (wc * 64 + t * 16 + ml) * 32 + quad * 8);
#pragma unroll
        for (int i = 0; i < 4; i++)
#pragma unroll
            for (int t = 0; t < 4; t++)
                acc[i][t] = __builtin_amdgcn_mfma_f32_16x16x32_bf16(af[i], bf[t], acc[i][t], 0, 0, 0);
    }

#pragma unroll
    for (int t = 0; t < 4; t++) {
        int c = colBase + wc * 64 + t * 16 + ml;
        float sv = g[c] * rsqrtf(rv[c] + BN_EPS);
        float tv = (bl[c] - rm[c]) * sv + bb[c];
#pragma unroll
        for (int i = 0; i < 4; i++) {
            int row0 = rowBase + wr * 64 + i * 16 + quad * 4;
#pragma unroll
            for (int r = 0; r < 4; r++) {
                int row = row0 + r;
                if (row < n) {
                    float v = acc[i][t][r] * sv + tv;
                    if (RELU) v = fmaxf(v, 0.f);
                    if constexpr (sizeof(OutT) == 2)
                        out[(size_t)row * HID + c] = (OutT)__float2bfloat16(v);
                    else
                        out[(size_t)row * HID + c] = (OutT)v;
                }
            }
        }
    }
}

extern "C" void kernel_launch(void* const* d_in, const int* in_sizes, int n_in,
                              void* d_out, int out_size, void* d_ws, size_t ws_size,
                              hipStream_t stream) {
    const float* x = (const float*)d_in[0];
    const int* ei = (const int*)d_in[1];
    const float *Wl[3], *blv[3], *Wr[3], *g[3], *bb[3], *rm[3], *rv[3];
    for (int i = 0; i < 3; i++) {
        int b = 2 + i * 7;
        Wl[i]  = (const float*)d_in[b + 0];
        blv[i] = (const float*)d_in[b + 1];
        Wr[i]  = (const float*)d_in[b + 2];
        g[i]   = (const float*)d_in[b + 3];
        bb[i]  = (const float*)d_in[b + 4];
        rm[i]  = (const float*)d_in[b + 5];
        rv[i]  = (const float*)d_in[b + 6];
    }

    // scratch inside d_out (fully overwritten by the final GEMM):
    char* ob = (char*)d_out;
    __hip_bfloat16* xb = (__hip_bfloat16*)ob;                              // 12.8 MB
    __hip_bfloat16* h0 = (__hip_bfloat16*)(ob + (size_t)NNODES * 128 * 2); // 25.6 MB

    char* w = (char*)d_ws;
    size_t off = 0;
    auto alloc = [&](size_t bytes) {
        void* p = w + off;
        off += (bytes + 255) & ~(size_t)255;
        return p;
    };
    int* rowptr = (int*)alloc((NNODES + 1) * sizeof(int));
    int* cnt    = (int*)alloc(NNODES * sizeof(int));
    int* loc    = (int*)alloc(NNODES * sizeof(int));
    int* bsum   = (int*)alloc(SCAN_B * sizeof(int));
    int* rank   = (int*)alloc(NEDGES * sizeof(int));
    int* col    = (int*)alloc(NEDGES * sizeof(int));
    __hip_bfloat16* meanb = (__hip_bfloat16*)alloc((size_t)NNODES * HID * 2);
    __hip_bfloat16* h1    = (__hip_bfloat16*)alloc((size_t)NNODES * HID * 2);
    __hip_bfloat16* Wt[6];
    int Ks[6] = {128, 128, 256, 256, 256, 256};
    for (int i = 0; i < 6; i++) Wt[i] = (__hip_bfloat16*)alloc((size_t)Ks[i] * HID * 2);

    // CSR build: one atomic pass + scan + pure scatter
    k_zero<<<SCAN_B, 256, 0, stream>>>(cnt, NNODES);
    k_countrank<<<(NEDGES + 255) / 256, 256, 0, stream>>>(ei, cnt, rank, NEDGES);
    k_bsum<<<SCAN_B, 256, 0, stream>>>(cnt, loc, bsum, NNODES);
    k_bscan<<<1, 256, 0, stream>>>(bsum, SCAN_B);
    k_addoff<<<SCAN_B, 256, 0, stream>>>(loc, bsum, rowptr, NNODES, NEDGES);
    k_fill2<<<(NEDGES + 255) / 256, 256, 0, stream>>>(ei, rowptr, rank, col, NEDGES);

    // x -> bf16
    k_cast<<<(NNODES * 128 / 4 + 255) / 256, 256, 0, stream>>>(x, xb, NNODES * 128);

    // fused weight transposes
    k_transpose6<<<(327680 + 255) / 256, 256, 0, stream>>>(
        Wl[0], Wr[0], Wl[1], Wr[1], Wl[2], Wr[2],
        Wt[0], Wt[1], Wt[2], Wt[3], Wt[4], Wt[5]);

    int meanBlocks = (NNODES * 64 + 255) / 256;
    int gemmBlocks = ((NNODES + 127) / 128) * 2;

    // layer 0 (K=128)
    k_mean<128><<<meanBlocks, 256, 0, stream>>>(xb, rowptr, col, meanb, NNODES);
    k_gemm<128, __hip_bfloat16, 1><<<gemmBlocks, 256, 0, stream>>>(meanb, xb, Wt[0], Wt[1],
        blv[0], g[0], bb[0], rm[0], rv[0], h0, NNODES);

    // layer 1 (K=256)
    k_mean<256><<<meanBlocks, 256, 0, stream>>>(h0, rowptr, col, meanb, NNODES);
    k_gemm<256, __hip_bfloat16, 1><<<gemmBlocks, 256, 0, stream>>>(meanb, h0, Wt[2], Wt[3],
        blv[1], g[1], bb[1], rm[1], rv[1], h1, NNODES);

    // layer 2 (K=256, no relu) -> f32 d_out
    k_mean<256><<<meanBlocks, 256, 0, stream>>>(h1, rowptr, col, meanb, NNODES);
    k_gemm<256, float, 0><<<gemmBlocks, 256, 0, stream>>>(meanb, h1, Wt[4], Wt[5],
        blv[2], g[2], bb[2], rm[2], rv[2], (float*)d_out, NNODES);
}

// Round 6
// 419.427 us; speedup vs baseline: 2.2129x; 1.0206x over previous
//
#include <hip/hip_runtime.h>
#include <hip/hip_bf16.h>

#define NNODES 50000
#define NEDGES 800000
#define HID 256
#define BN_EPS 1e-5f
#define SCAN_B ((NNODES + 255) / 256)   // 196 blocks

typedef __attribute__((ext_vector_type(8))) short short8v;
typedef __attribute__((ext_vector_type(4))) float f32x4;

__device__ inline void load_lds16(const void* g, void* l) {
    __builtin_amdgcn_global_load_lds(
        (const __attribute__((address_space(1))) unsigned int*)g,
        (__attribute__((address_space(3))) unsigned int*)l, 16, 0, 0);
}

// ---------------- CSR build ----------------
__global__ void k_zero(int* p, int n) {
    int i = blockIdx.x * blockDim.x + threadIdx.x;
    if (i < n) p[i] = 0;
}

// count AND rank in a single atomic pass
__global__ void k_countrank(const int* __restrict__ ei, int* __restrict__ cnt,
                            int* __restrict__ rank, int nE) {
    int e = blockIdx.x * blockDim.x + threadIdx.x;
    if (e < nE) rank[e] = atomicAdd(&cnt[ei[nE + e]], 1);
}

__global__ void k_bsum(const int* __restrict__ cnt, int* __restrict__ loc,
                       int* __restrict__ bsum, int n) {
    __shared__ int sh[256];
    int tid = threadIdx.x;
    int i = blockIdx.x * 256 + tid;
    int v = (i < n) ? cnt[i] : 0;
    sh[tid] = v;
    __syncthreads();
    for (int off = 1; off < 256; off <<= 1) {
        int t = (tid >= off) ? sh[tid - off] : 0;
        __syncthreads();
        sh[tid] += t;
        __syncthreads();
    }
    if (i < n) loc[i] = sh[tid] - v;          // exclusive
    if (tid == 255) bsum[blockIdx.x] = sh[255];
}

__global__ void k_bscan(int* __restrict__ bsum, int nb) {
    __shared__ int sh[256];
    int tid = threadIdx.x;
    int v = (tid < nb) ? bsum[tid] : 0;
    sh[tid] = v;
    __syncthreads();
    for (int off = 1; off < 256; off <<= 1) {
        int t = (tid >= off) ? sh[tid - off] : 0;
        __syncthreads();
        sh[tid] += t;
        __syncthreads();
    }
    if (tid < nb) bsum[tid] = sh[tid] - v;    // exclusive
}

__global__ void k_addoff(const int* __restrict__ loc, const int* __restrict__ bsum,
                         int* __restrict__ rowptr, int n, int nE) {
    int i = blockIdx.x * 256 + threadIdx.x;
    if (i < n) rowptr[i] = loc[i] + bsum[blockIdx.x];
    if (i == 0) rowptr[n] = nE;
}

__global__ void k_fill2(const int* __restrict__ ei, const int* __restrict__ rowptr,
                        const int* __restrict__ rank, int* __restrict__ col, int nE) {
    int e = blockIdx.x * blockDim.x + threadIdx.x;
    if (e < nE) col[rowptr[ei[nE + e]] + rank[e]] = ei[e];
}

// ---------------- cast f32 -> bf16 ----------------
__global__ void k_cast(const float* __restrict__ in, __hip_bfloat16* __restrict__ out, int n) {
    int i = blockIdx.x * blockDim.x + threadIdx.x;
    int base = i * 4;
    if (base + 3 < n) {
        float4 v = *(const float4*)(in + base);
        out[base + 0] = __float2bfloat16(v.x);
        out[base + 1] = __float2bfloat16(v.y);
        out[base + 2] = __float2bfloat16(v.z);
        out[base + 3] = __float2bfloat16(v.w);
    } else {
        for (int j = base; j < n; j++) out[j] = __float2bfloat16(in[j]);
    }
}

// ---------------- fused weight transpose ----------------
__global__ void k_transpose6(const float* __restrict__ s0, const float* __restrict__ s1,
                             const float* __restrict__ s2, const float* __restrict__ s3,
                             const float* __restrict__ s4, const float* __restrict__ s5,
                             __hip_bfloat16* __restrict__ d0, __hip_bfloat16* __restrict__ d1,
                             __hip_bfloat16* __restrict__ d2, __hip_bfloat16* __restrict__ d3,
                             __hip_bfloat16* __restrict__ d4, __hip_bfloat16* __restrict__ d5) {
    int f = blockIdx.x * blockDim.x + threadIdx.x;   // 0 .. 327679
    const float* src; __hip_bfloat16* dst; int K; int i;
    if (f < 65536) {
        K = 128;
        if (f < 32768) { src = s0; dst = d0; i = f; }
        else           { src = s1; dst = d1; i = f - 32768; }
    } else {
        K = 256;
        int r = f - 65536;
        int wsel = r >> 16;
        i = r & 65535;
        src = (wsel == 0) ? s2 : (wsel == 1) ? s3 : (wsel == 2) ? s4 : s5;
        dst = (wsel == 0) ? d2 : (wsel == 1) ? d3 : (wsel == 2) ? d4 : d5;
    }
    int k = i >> 8;
    int nn = i & 255;
    dst[nn * K + k] = __float2bfloat16(src[i]);
}

// ---------------- mean aggregation: wave/node, 16B/lane, U*R neighbors in flight
// D bf16/row; CPL = D/8 lanes per row; R = 64/CPL rows per sub-step; U unroll.
template <int D, int U>
__global__ void k_mean(const __hip_bfloat16* __restrict__ xin,
                       const int* __restrict__ rowptr, const int* __restrict__ col,
                       __hip_bfloat16* __restrict__ mean, int n) {
    constexpr int CPL = D / 8;
    constexpr int R = 64 / CPL;
    int gw = (blockIdx.x * blockDim.x + threadIdx.x) >> 6;
    int lane = threadIdx.x & 63;
    if (gw >= n) return;
    int beg = rowptr[gw], end = rowptr[gw + 1];
    int sub = lane / CPL;
    int fpos = lane % CPL;
    const uint4* base = (const uint4*)xin;

    float acc[8];
#pragma unroll
    for (int j = 0; j < 8; j++) acc[j] = 0.f;

    for (int p0 = beg; p0 < end; p0 += U * R) {
        int idx[U]; bool ok[U];
#pragma unroll
        for (int u = 0; u < U; u++) {
            int p = p0 + u * R + sub;
            ok[u] = (p < end);
            idx[u] = ok[u] ? col[p] : 0;
        }
        uint4 v[U];
#pragma unroll
        for (int u = 0; u < U; u++) {
            uint4 t = {0u, 0u, 0u, 0u};
            if (ok[u]) t = base[(size_t)idx[u] * CPL + fpos];
            v[u] = t;
        }
#pragma unroll
        for (int u = 0; u < U; u++) {
            const unsigned int uu[4] = {v[u].x, v[u].y, v[u].z, v[u].w};
#pragma unroll
            for (int j = 0; j < 4; j++) {
                acc[2 * j]     += __uint_as_float(uu[j] << 16);
                acc[2 * j + 1] += __uint_as_float(uu[j] & 0xffff0000u);
            }
        }
    }

    if constexpr (R >= 2) {
#pragma unroll
        for (int j = 0; j < 8; j++) acc[j] += __shfl_xor(acc[j], 32, 64);
    }
    if constexpr (R == 4) {
#pragma unroll
        for (int j = 0; j < 8; j++) acc[j] += __shfl_xor(acc[j], 16, 64);
    }

    if (sub == 0) {
        float inv = (end > beg) ? 1.f / (float)(end - beg) : 0.f;
        union { uint4 v; unsigned short s[8]; } o;
#pragma unroll
        for (int j = 0; j < 8; j++)
            o.s[j] = __bfloat16_as_ushort(__float2bfloat16(acc[j] * inv));
        *(uint4*)(mean + (size_t)gw * D + fpos * 8) = o.v;
    }
}

// ---------------- fused GEMM + BN (+ReLU): dual-pass staging, 32 MFMA/barrier
// out[n,256] = act( (A1@W1 + A2@W2 + bl - rm) * scale + shift )
template <int K, typename OutT, int RELU>
__launch_bounds__(256)
__global__ void k_gemm(const __hip_bfloat16* __restrict__ A1,
                       const __hip_bfloat16* __restrict__ A2,
                       const __hip_bfloat16* __restrict__ W1t,
                       const __hip_bfloat16* __restrict__ W2t,
                       const float* __restrict__ bl,
                       const float* __restrict__ g,
                       const float* __restrict__ bb,
                       const float* __restrict__ rm,
                       const float* __restrict__ rv,
                       OutT* __restrict__ out, int n) {
    __shared__ __hip_bfloat16 As1[128 * 32];   // 8 KB each, 32 KB total
    __shared__ __hip_bfloat16 As2[128 * 32];
    __shared__ __hip_bfloat16 Bs1[128 * 32];
    __shared__ __hip_bfloat16 Bs2[128 * 32];
    int tid = threadIdx.x;
    int lane = tid & 63;
    int w = tid >> 6;
    int quad = lane >> 4;
    int ml = lane & 15;
    int rowBase = (blockIdx.x >> 1) * 128;
    int colBase = (blockIdx.x & 1) * 128;
    int wr = w >> 1, wc = w & 1;

    f32x4 acc[4][4];
#pragma unroll
    for (int i = 0; i < 4; i++)
#pragma unroll
        for (int t = 0; t < 4; t++) acc[i][t] = {0.f, 0.f, 0.f, 0.f};

    int srow = tid >> 2;
    int sbyte = (tid & 3) * 16;

    for (int k0 = 0; k0 < K; k0 += 32) {
        __syncthreads();   // previous iter's ds_reads done before overwrite
#pragma unroll
        for (int h = 0; h < 2; h++) {
            int r = srow + h * 64;
            int grow = rowBase + r; if (grow >= n) grow = n - 1;
            int c = colBase + r;
            load_lds16((const char*)(A1 + (size_t)grow * K + k0) + sbyte,
                       (char*)As1 + r * 64 + sbyte);
            load_lds16((const char*)(A2 + (size_t)grow * K + k0) + sbyte,
                       (char*)As2 + r * 64 + sbyte);
            load_lds16((const char*)(W1t + (size_t)c * K + k0) + sbyte,
                       (char*)Bs1 + r * 64 + sbyte);
            load_lds16((const char*)(W2t + (size_t)c * K + k0) + sbyte,
                       (char*)Bs2 + r * 64 + sbyte);
        }
        __syncthreads();   // staging visible

        short8v af1[4], af2[4], bf1[4], bf2[4];
#pragma unroll
        for (int i = 0; i < 4; i++) {
            af1[i] = *(const short8v*)(As1 + (wr * 64 + i * 16 + ml) * 32 + quad * 8);
            af2[i] = *(const short8v*)(As2 + (wr * 64 + i * 16 + ml) * 32 + quad * 8);
        }
#pragma unroll
        for (int t = 0; t < 4; t++) {
            bf1[t] = *(const short8v*)(Bs1 + (wc * 64 + t * 16 + ml) * 32 + quad * 8);
            bf2[t] = *(const short8v*)(Bs2 + (wc * 64 + t * 16 + ml) * 32 + quad * 8);
        }
#pragma unroll
        for (int i = 0; i < 4; i++)
#pragma unroll
            for (int t = 0; t < 4; t++) {
                acc[i][t] = __builtin_amdgcn_mfma_f32_16x16x32_bf16(af1[i], bf1[t], acc[i][t], 0, 0, 0);
                acc[i][t] = __builtin_amdgcn_mfma_f32_16x16x32_bf16(af2[i], bf2[t], acc[i][t], 0, 0, 0);
            }
    }

#pragma unroll
    for (int t = 0; t < 4; t++) {
        int c = colBase + wc * 64 + t * 16 + ml;
        float sv = g[c] * rsqrtf(rv[c] + BN_EPS);
        float tv = (bl[c] - rm[c]) * sv + bb[c];
#pragma unroll
        for (int i = 0; i < 4; i++) {
            int row0 = rowBase + wr * 64 + i * 16 + quad * 4;
#pragma unroll
            for (int r = 0; r < 4; r++) {
                int row = row0 + r;
                if (row < n) {
                    float v = acc[i][t][r] * sv + tv;
                    if (RELU) v = fmaxf(v, 0.f);
                    if constexpr (sizeof(OutT) == 2)
                        out[(size_t)row * HID + c] = (OutT)__float2bfloat16(v);
                    else
                        out[(size_t)row * HID + c] = (OutT)v;
                }
            }
        }
    }
}

extern "C" void kernel_launch(void* const* d_in, const int* in_sizes, int n_in,
                              void* d_out, int out_size, void* d_ws, size_t ws_size,
                              hipStream_t stream) {
    const float* x = (const float*)d_in[0];
    const int* ei = (const int*)d_in[1];
    const float *Wl[3], *blv[3], *Wr[3], *g[3], *bb[3], *rm[3], *rv[3];
    for (int i = 0; i < 3; i++) {
        int b = 2 + i * 7;
        Wl[i]  = (const float*)d_in[b + 0];
        blv[i] = (const float*)d_in[b + 1];
        Wr[i]  = (const float*)d_in[b + 2];
        g[i]   = (const float*)d_in[b + 3];
        bb[i]  = (const float*)d_in[b + 4];
        rm[i]  = (const float*)d_in[b + 5];
        rv[i]  = (const float*)d_in[b + 6];
    }

    // scratch inside d_out (fully overwritten by the final GEMM):
    char* ob = (char*)d_out;
    __hip_bfloat16* xb = (__hip_bfloat16*)ob;                              // 12.8 MB
    __hip_bfloat16* h0 = (__hip_bfloat16*)(ob + (size_t)NNODES * 128 * 2); // 25.6 MB

    char* w = (char*)d_ws;
    size_t off = 0;
    auto alloc = [&](size_t bytes) {
        void* p = w + off;
        off += (bytes + 255) & ~(size_t)255;
        return p;
    };
    int* rowptr = (int*)alloc((NNODES + 1) * sizeof(int));
    int* cnt    = (int*)alloc(NNODES * sizeof(int));
    int* loc    = (int*)alloc(NNODES * sizeof(int));
    int* bsum   = (int*)alloc(SCAN_B * sizeof(int));
    int* rank   = (int*)alloc(NEDGES * sizeof(int));
    int* col    = (int*)alloc(NEDGES * sizeof(int));
    __hip_bfloat16* meanb = (__hip_bfloat16*)alloc((size_t)NNODES * HID * 2);
    __hip_bfloat16* h1    = (__hip_bfloat16*)alloc((size_t)NNODES * HID * 2);
    __hip_bfloat16* Wt[6];
    int Ks[6] = {128, 128, 256, 256, 256, 256};
    for (int i = 0; i < 6; i++) Wt[i] = (__hip_bfloat16*)alloc((size_t)Ks[i] * HID * 2);

    // CSR build: one atomic pass + scan + pure scatter
    k_zero<<<SCAN_B, 256, 0, stream>>>(cnt, NNODES);
    k_countrank<<<(NEDGES + 255) / 256, 256, 0, stream>>>(ei, cnt, rank, NEDGES);
    k_bsum<<<SCAN_B, 256, 0, stream>>>(cnt, loc, bsum, NNODES);
    k_bscan<<<1, 256, 0, stream>>>(bsum, SCAN_B);
    k_addoff<<<SCAN_B, 256, 0, stream>>>(loc, bsum, rowptr, NNODES, NEDGES);
    k_fill2<<<(NEDGES + 255) / 256, 256, 0, stream>>>(ei, rowptr, rank, col, NEDGES);

    // x -> bf16
    k_cast<<<(NNODES * 128 / 4 + 255) / 256, 256, 0, stream>>>(x, xb, NNODES * 128);

    // fused weight transposes
    k_transpose6<<<(327680 + 255) / 256, 256, 0, stream>>>(
        Wl[0], Wr[0], Wl[1], Wr[1], Wl[2], Wr[2],
        Wt[0], Wt[1], Wt[2], Wt[3], Wt[4], Wt[5]);

    int meanBlocks = (NNODES * 64 + 255) / 256;
    int gemmBlocks = ((NNODES + 127) / 128) * 2;

    // layer 0 (K=128): U=4, R=4 -> 16 neighbors in flight
    k_mean<128, 4><<<meanBlocks, 256, 0, stream>>>(xb, rowptr, col, meanb, NNODES);
    k_gemm<128, __hip_bfloat16, 1><<<gemmBlocks, 256, 0, stream>>>(meanb, xb, Wt[0], Wt[1],
        blv[0], g[0], bb[0], rm[0], rv[0], h0, NNODES);

    // layer 1 (K=256): U=8, R=2 -> 16 neighbors in flight
    k_mean<256, 8><<<meanBlocks, 256, 0, stream>>>(h0, rowptr, col, meanb, NNODES);
    k_gemm<256, __hip_bfloat16, 1><<<gemmBlocks, 256, 0, stream>>>(meanb, h0, Wt[2], Wt[3],
        blv[1], g[1], bb[1], rm[1], rv[1], h1, NNODES);

    // layer 2 (K=256, no relu) -> f32 d_out
    k_mean<256, 8><<<meanBlocks, 256, 0, stream>>>(h1, rowptr, col, meanb, NNODES);
    k_gemm<256, float, 0><<<gemmBlocks, 256, 0, stream>>>(meanb, h1, Wt[4], Wt[5],
        blv[2], g[2], bb[2], rm[2], rv[2], (float*)d_out, NNODES);
}

// Round 7
// 411.223 us; speedup vs baseline: 2.2571x; 1.0199x over previous
//
#include <hip/hip_runtime.h>
#include <hip/hip_bf16.h>

#define NNODES 50000
#define NEDGES 800000
#define HID 256
#define BN_EPS 1e-5f
#define SCAN_B ((NNODES + 255) / 256)   // 196 blocks

typedef __attribute__((ext_vector_type(8))) short short8v;
typedef __attribute__((ext_vector_type(4))) float f32x4;

__device__ inline void load_lds16(const void* g, void* l) {
    __builtin_amdgcn_global_load_lds(
        (const __attribute__((address_space(1))) unsigned int*)g,
        (__attribute__((address_space(3))) unsigned int*)l, 16, 0, 0);
}

// ---------------- CSR build ----------------
__global__ void k_zero(int* p, int n) {
    int i = blockIdx.x * blockDim.x + threadIdx.x;
    if (i < n) p[i] = 0;
}

__global__ void k_countrank(const int* __restrict__ ei, int* __restrict__ cnt,
                            int* __restrict__ rank, int nE) {
    int e = blockIdx.x * blockDim.x + threadIdx.x;
    if (e < nE) rank[e] = atomicAdd(&cnt[ei[nE + e]], 1);
}

__global__ void k_bsum(const int* __restrict__ cnt, int* __restrict__ loc,
                       int* __restrict__ bsum, int n) {
    __shared__ int sh[256];
    int tid = threadIdx.x;
    int i = blockIdx.x * 256 + tid;
    int v = (i < n) ? cnt[i] : 0;
    sh[tid] = v;
    __syncthreads();
    for (int off = 1; off < 256; off <<= 1) {
        int t = (tid >= off) ? sh[tid - off] : 0;
        __syncthreads();
        sh[tid] += t;
        __syncthreads();
    }
    if (i < n) loc[i] = sh[tid] - v;
    if (tid == 255) bsum[blockIdx.x] = sh[255];
}

__global__ void k_bscan(int* __restrict__ bsum, int nb) {
    __shared__ int sh[256];
    int tid = threadIdx.x;
    int v = (tid < nb) ? bsum[tid] : 0;
    sh[tid] = v;
    __syncthreads();
    for (int off = 1; off < 256; off <<= 1) {
        int t = (tid >= off) ? sh[tid - off] : 0;
        __syncthreads();
        sh[tid] += t;
        __syncthreads();
    }
    if (tid < nb) bsum[tid] = sh[tid] - v;
}

__global__ void k_addoff(const int* __restrict__ loc, const int* __restrict__ bsum,
                         int* __restrict__ rowptr, int n, int nE) {
    int i = blockIdx.x * 256 + threadIdx.x;
    if (i < n) rowptr[i] = loc[i] + bsum[blockIdx.x];
    if (i == 0) rowptr[n] = nE;
}

__global__ void k_fill2(const int* __restrict__ ei, const int* __restrict__ rowptr,
                        const int* __restrict__ rank, int* __restrict__ col, int nE) {
    int e = blockIdx.x * blockDim.x + threadIdx.x;
    if (e < nE) col[rowptr[ei[nE + e]] + rank[e]] = ei[e];
}

// ---------------- cast f32 -> bf16 ----------------
__global__ void k_cast(const float* __restrict__ in, __hip_bfloat16* __restrict__ out, int n) {
    int i = blockIdx.x * blockDim.x + threadIdx.x;
    int base = i * 4;
    if (base + 3 < n) {
        float4 v = *(const float4*)(in + base);
        out[base + 0] = __float2bfloat16(v.x);
        out[base + 1] = __float2bfloat16(v.y);
        out[base + 2] = __float2bfloat16(v.z);
        out[base + 3] = __float2bfloat16(v.w);
    } else {
        for (int j = base; j < n; j++) out[j] = __float2bfloat16(in[j]);
    }
}

// ---------------- fused weight transpose ----------------
__global__ void k_transpose6(const float* __restrict__ s0, const float* __restrict__ s1,
                             const float* __restrict__ s2, const float* __restrict__ s3,
                             const float* __restrict__ s4, const float* __restrict__ s5,
                             __hip_bfloat16* __restrict__ d0, __hip_bfloat16* __restrict__ d1,
                             __hip_bfloat16* __restrict__ d2, __hip_bfloat16* __restrict__ d3,
                             __hip_bfloat16* __restrict__ d4, __hip_bfloat16* __restrict__ d5) {
    int f = blockIdx.x * blockDim.x + threadIdx.x;   // 0 .. 327679
    const float* src; __hip_bfloat16* dst; int K; int i;
    if (f < 65536) {
        K = 128;
        if (f < 32768) { src = s0; dst = d0; i = f; }
        else           { src = s1; dst = d1; i = f - 32768; }
    } else {
        K = 256;
        int r = f - 65536;
        int wsel = r >> 16;
        i = r & 65535;
        src = (wsel == 0) ? s2 : (wsel == 1) ? s3 : (wsel == 2) ? s4 : s5;
        dst = (wsel == 0) ? d2 : (wsel == 1) ? d3 : (wsel == 2) ? d4 : d5;
    }
    int k = i >> 8;
    int nn = i & 255;
    dst[nn * K + k] = __float2bfloat16(src[i]);
}

// ---------------- mean aggregation, 128-feature slice per dispatch ----------
// Row stride D bf16; this dispatch covers features [fo, fo+128).
// 16 lanes per row (16B each), 4 neighbors per sub-step, U=4 unroll.
template <int D, int U>
__global__ void k_meanh(const __hip_bfloat16* __restrict__ xin,
                        const int* __restrict__ rowptr, const int* __restrict__ col,
                        __hip_bfloat16* __restrict__ mean, int n, int fo) {
    constexpr int QPR = D / 8;        // uint4 per full row
    int gw = (blockIdx.x * blockDim.x + threadIdx.x) >> 6;
    int lane = threadIdx.x & 63;
    if (gw >= n) return;
    int beg = rowptr[gw], end = rowptr[gw + 1];
    int sub = lane >> 4;              // neighbor slot 0..3
    int fpos = lane & 15;             // 16B chunk within the 128-feat slice
    const uint4* base = (const uint4*)xin;
    int foq = fo >> 3;                // slice offset in uint4

    float acc[8];
#pragma unroll
    for (int j = 0; j < 8; j++) acc[j] = 0.f;

    for (int p0 = beg; p0 < end; p0 += U * 4) {
        int idx[U]; bool ok[U];
#pragma unroll
        for (int u = 0; u < U; u++) {
            int p = p0 + u * 4 + sub;
            ok[u] = (p < end);
            idx[u] = ok[u] ? col[p] : 0;
        }
        uint4 v[U];
#pragma unroll
        for (int u = 0; u < U; u++) {
            uint4 t = {0u, 0u, 0u, 0u};
            if (ok[u]) t = base[(size_t)idx[u] * QPR + foq + fpos];
            v[u] = t;
        }
#pragma unroll
        for (int u = 0; u < U; u++) {
            const unsigned int uu[4] = {v[u].x, v[u].y, v[u].z, v[u].w};
#pragma unroll
            for (int j = 0; j < 4; j++) {
                acc[2 * j]     += __uint_as_float(uu[j] << 16);
                acc[2 * j + 1] += __uint_as_float(uu[j] & 0xffff0000u);
            }
        }
    }

    // reduce across the 4 neighbor slots (lanes sharing fpos)
#pragma unroll
    for (int j = 0; j < 8; j++) acc[j] += __shfl_xor(acc[j], 32, 64);
#pragma unroll
    for (int j = 0; j < 8; j++) acc[j] += __shfl_xor(acc[j], 16, 64);

    if (sub == 0) {
        float inv = (end > beg) ? 1.f / (float)(end - beg) : 0.f;
        union { uint4 v; unsigned short s[8]; } o;
#pragma unroll
        for (int j = 0; j < 8; j++)
            o.s[j] = __bfloat16_as_ushort(__float2bfloat16(acc[j] * inv));
        *(uint4*)(mean + (size_t)gw * D + fo + fpos * 8) = o.v;
    }
}

// ---------------- fused GEMM + BN (+ReLU): 128x256 tile, 64 MFMA/barrier ----
// out[n,256] = act( (A1@W1 + A2@W2 + bl - rm) * scale + shift )
// Full output width per block: A1/A2 read exactly once.
template <int K, typename OutT, int RELU>
__launch_bounds__(256, 2)
__global__ void k_gemm2(const __hip_bfloat16* __restrict__ A1,
                        const __hip_bfloat16* __restrict__ A2,
                        const __hip_bfloat16* __restrict__ W1t,
                        const __hip_bfloat16* __restrict__ W2t,
                        const float* __restrict__ bl,
                        const float* __restrict__ g,
                        const float* __restrict__ bb,
                        const float* __restrict__ rm,
                        const float* __restrict__ rv,
                        OutT* __restrict__ out, int n) {
    __shared__ __hip_bfloat16 As1[128 * 32];   // 8 KB
    __shared__ __hip_bfloat16 As2[128 * 32];   // 8 KB
    __shared__ __hip_bfloat16 Bs1[256 * 32];   // 16 KB
    __shared__ __hip_bfloat16 Bs2[256 * 32];   // 16 KB
    int tid = threadIdx.x;
    int lane = tid & 63;
    int w = tid >> 6;
    int quad = lane >> 4;
    int ml = lane & 15;
    int rowBase = blockIdx.x * 128;
    int wr = w >> 1, wc = w & 1;   // wave covers rows [wr*64,+64), cols [wc*128,+128)

    f32x4 acc[4][8];
#pragma unroll
    for (int i = 0; i < 4; i++)
#pragma unroll
        for (int t = 0; t < 8; t++) acc[i][t] = {0.f, 0.f, 0.f, 0.f};

    int srow = tid >> 2;              // 0..63
    int sbyte = (tid & 3) * 16;

    for (int k0 = 0; k0 < K; k0 += 32) {
        __syncthreads();
#pragma unroll
        for (int h = 0; h < 2; h++) {
            int r = srow + h * 64;
            int grow = rowBase + r; if (grow >= n) grow = n - 1;
            load_lds16((const char*)(A1 + (size_t)grow * K + k0) + sbyte,
                       (char*)As1 + r * 64 + sbyte);
            load_lds16((const char*)(A2 + (size_t)grow * K + k0) + sbyte,
                       (char*)As2 + r * 64 + sbyte);
        }
#pragma unroll
        for (int h = 0; h < 4; h++) {
            int c = srow + h * 64;
            load_lds16((const char*)(W1t + (size_t)c * K + k0) + sbyte,
                       (char*)Bs1 + c * 64 + sbyte);
            load_lds16((const char*)(W2t + (size_t)c * K + k0) + sbyte,
                       (char*)Bs2 + c * 64 + sbyte);
        }
        __syncthreads();

        short8v af1[4], af2[4];
#pragma unroll
        for (int i = 0; i < 4; i++) {
            af1[i] = *(const short8v*)(As1 + (wr * 64 + i * 16 + ml) * 32 + quad * 8);
            af2[i] = *(const short8v*)(As2 + (wr * 64 + i * 16 + ml) * 32 + quad * 8);
        }
#pragma unroll
        for (int t = 0; t < 8; t++) {
            short8v bf1 = *(const short8v*)(Bs1 + (wc * 128 + t * 16 + ml) * 32 + quad * 8);
            short8v bf2 = *(const short8v*)(Bs2 + (wc * 128 + t * 16 + ml) * 32 + quad * 8);
#pragma unroll
            for (int i = 0; i < 4; i++) {
                acc[i][t] = __builtin_amdgcn_mfma_f32_16x16x32_bf16(af1[i], bf1, acc[i][t], 0, 0, 0);
                acc[i][t] = __builtin_amdgcn_mfma_f32_16x16x32_bf16(af2[i], bf2, acc[i][t], 0, 0, 0);
            }
        }
    }

#pragma unroll
    for (int t = 0; t < 8; t++) {
        int c = wc * 128 + t * 16 + ml;
        float sv = g[c] * rsqrtf(rv[c] + BN_EPS);
        float tv = (bl[c] - rm[c]) * sv + bb[c];
#pragma unroll
        for (int i = 0; i < 4; i++) {
            int row0 = rowBase + wr * 64 + i * 16 + quad * 4;
#pragma unroll
            for (int r = 0; r < 4; r++) {
                int row = row0 + r;
                if (row < n) {
                    float v = acc[i][t][r] * sv + tv;
                    if (RELU) v = fmaxf(v, 0.f);
                    if constexpr (sizeof(OutT) == 2)
                        out[(size_t)row * HID + c] = (OutT)__float2bfloat16(v);
                    else
                        out[(size_t)row * HID + c] = (OutT)v;
                }
            }
        }
    }
}

extern "C" void kernel_launch(void* const* d_in, const int* in_sizes, int n_in,
                              void* d_out, int out_size, void* d_ws, size_t ws_size,
                              hipStream_t stream) {
    const float* x = (const float*)d_in[0];
    const int* ei = (const int*)d_in[1];
    const float *Wl[3], *blv[3], *Wr[3], *g[3], *bb[3], *rm[3], *rv[3];
    for (int i = 0; i < 3; i++) {
        int b = 2 + i * 7;
        Wl[i]  = (const float*)d_in[b + 0];
        blv[i] = (const float*)d_in[b + 1];
        Wr[i]  = (const float*)d_in[b + 2];
        g[i]   = (const float*)d_in[b + 3];
        bb[i]  = (const float*)d_in[b + 4];
        rm[i]  = (const float*)d_in[b + 5];
        rv[i]  = (const float*)d_in[b + 6];
    }

    // scratch inside d_out (fully overwritten by the final GEMM):
    char* ob = (char*)d_out;
    __hip_bfloat16* xb = (__hip_bfloat16*)ob;                              // 12.8 MB
    __hip_bfloat16* h0 = (__hip_bfloat16*)(ob + (size_t)NNODES * 128 * 2); // 25.6 MB

    char* w = (char*)d_ws;
    size_t off = 0;
    auto alloc = [&](size_t bytes) {
        void* p = w + off;
        off += (bytes + 255) & ~(size_t)255;
        return p;
    };
    int* rowptr = (int*)alloc((NNODES + 1) * sizeof(int));
    int* cnt    = (int*)alloc(NNODES * sizeof(int));
    int* loc    = (int*)alloc(NNODES * sizeof(int));
    int* bsum   = (int*)alloc(SCAN_B * sizeof(int));
    int* rank   = (int*)alloc(NEDGES * sizeof(int));
    int* col    = (int*)alloc(NEDGES * sizeof(int));
    __hip_bfloat16* meanb = (__hip_bfloat16*)alloc((size_t)NNODES * HID * 2);
    __hip_bfloat16* h1    = (__hip_bfloat16*)alloc((size_t)NNODES * HID * 2);
    __hip_bfloat16* Wt[6];
    int Ks[6] = {128, 128, 256, 256, 256, 256};
    for (int i = 0; i < 6; i++) Wt[i] = (__hip_bfloat16*)alloc((size_t)Ks[i] * HID * 2);

    // CSR build
    k_zero<<<SCAN_B, 256, 0, stream>>>(cnt, NNODES);
    k_countrank<<<(NEDGES + 255) / 256, 256, 0, stream>>>(ei, cnt, rank, NEDGES);
    k_bsum<<<SCAN_B, 256, 0, stream>>>(cnt, loc, bsum, NNODES);
    k_bscan<<<1, 256, 0, stream>>>(bsum, SCAN_B);
    k_addoff<<<SCAN_B, 256, 0, stream>>>(loc, bsum, rowptr, NNODES, NEDGES);
    k_fill2<<<(NEDGES + 255) / 256, 256, 0, stream>>>(ei, rowptr, rank, col, NEDGES);

    // x -> bf16
    k_cast<<<(NNODES * 128 / 4 + 255) / 256, 256, 0, stream>>>(x, xb, NNODES * 128);

    // fused weight transposes
    k_transpose6<<<(327680 + 255) / 256, 256, 0, stream>>>(
        Wl[0], Wr[0], Wl[1], Wr[1], Wl[2], Wr[2],
        Wt[0], Wt[1], Wt[2], Wt[3], Wt[4], Wt[5]);

    int meanBlocks = (NNODES * 64 + 255) / 256;      // one wave per node
    int gemmBlocks = (NNODES + 127) / 128;           // 391, full 256-col tiles

    // layer 0 (K=128): single 128-feat slice
    k_meanh<128, 4><<<meanBlocks, 256, 0, stream>>>(xb, rowptr, col, meanb, NNODES, 0);
    k_gemm2<128, __hip_bfloat16, 1><<<gemmBlocks, 256, 0, stream>>>(meanb, xb, Wt[0], Wt[1],
        blv[0], g[0], bb[0], rm[0], rv[0], h0, NNODES);

    // layer 1 (K=256): two 128-feat slices (working-set halving)
    k_meanh<256, 4><<<meanBlocks, 256, 0, stream>>>(h0, rowptr, col, meanb, NNODES, 0);
    k_meanh<256, 4><<<meanBlocks, 256, 0, stream>>>(h0, rowptr, col, meanb, NNODES, 128);
    k_gemm2<256, __hip_bfloat16, 1><<<gemmBlocks, 256, 0, stream>>>(meanb, h0, Wt[2], Wt[3],
        blv[1], g[1], bb[1], rm[1], rv[1], h1, NNODES);

    // layer 2 (K=256, no relu) -> f32 d_out
    k_meanh<256, 4><<<meanBlocks, 256, 0, stream>>>(h1, rowptr, col, meanb, NNODES, 0);
    k_meanh<256, 4><<<meanBlocks, 256, 0, stream>>>(h1, rowptr, col, meanb, NNODES, 128);
    k_gemm2<256, float, 0><<<gemmBlocks, 256, 0, stream>>>(meanb, h1, Wt[4], Wt[5],
        blv[2], g[2], bb[2], rm[2], rv[2], (float*)d_out, NNODES);
}

// Round 8
// 376.017 us; speedup vs baseline: 2.4684x; 1.0936x over previous
//
#include <hip/hip_runtime.h>
#include <hip/hip_bf16.h>

#define NNODES 50000
#define NEDGES 800000
#define HID 256
#define BN_EPS 1e-5f
#define SCAN_B ((NNODES + 255) / 256)   // 196 blocks

typedef __attribute__((ext_vector_type(8))) short short8v;
typedef __attribute__((ext_vector_type(4))) float f32x4;
typedef __attribute__((ext_vector_type(2))) float f32x2;

__device__ inline void load_lds16(const void* g, void* l) {
    __builtin_amdgcn_global_load_lds(
        (const __attribute__((address_space(1))) unsigned int*)g,
        (__attribute__((address_space(3))) unsigned int*)l, 16, 0, 0);
}

// ---------------- CSR build ----------------
__global__ void k_countrank(const int* __restrict__ ei, int* __restrict__ cnt,
                            int* __restrict__ rank, int nE) {
    int e = blockIdx.x * blockDim.x + threadIdx.x;
    if (e < nE) rank[e] = atomicAdd(&cnt[ei[nE + e]], 1);
}

__global__ void k_bsum(const int* __restrict__ cnt, int* __restrict__ loc,
                       int* __restrict__ bsum, int n) {
    __shared__ int sh[256];
    int tid = threadIdx.x;
    int i = blockIdx.x * 256 + tid;
    int v = (i < n) ? cnt[i] : 0;
    sh[tid] = v;
    __syncthreads();
    for (int off = 1; off < 256; off <<= 1) {
        int t = (tid >= off) ? sh[tid - off] : 0;
        __syncthreads();
        sh[tid] += t;
        __syncthreads();
    }
    if (i < n) loc[i] = sh[tid] - v;
    if (tid == 255) bsum[blockIdx.x] = sh[255];
}

__global__ void k_bscan(int* __restrict__ bsum, int nb) {
    __shared__ int sh[256];
    int tid = threadIdx.x;
    int v = (tid < nb) ? bsum[tid] : 0;
    sh[tid] = v;
    __syncthreads();
    for (int off = 1; off < 256; off <<= 1) {
        int t = (tid >= off) ? sh[tid - off] : 0;
        __syncthreads();
        sh[tid] += t;
        __syncthreads();
    }
    if (tid < nb) bsum[tid] = sh[tid] - v;
}

__global__ void k_addoff(const int* __restrict__ loc, const int* __restrict__ bsum,
                         int* __restrict__ rowptr, int n, int nE) {
    int i = blockIdx.x * 256 + threadIdx.x;
    if (i < n) rowptr[i] = loc[i] + bsum[blockIdx.x];
    if (i == 0) rowptr[n] = nE;
}

__global__ void k_fill2(const int* __restrict__ ei, const int* __restrict__ rowptr,
                        const int* __restrict__ rank, int* __restrict__ col, int nE) {
    int e = blockIdx.x * blockDim.x + threadIdx.x;
    if (e < nE) col[rowptr[ei[nE + e]] + rank[e]] = ei[e];
}

// ---------------- fused prep: cast x->bf16+fp8, transpose weights, zero cnt
// ranges: [0,1600000) cast float4 ; [.., +327680) transpose ; [.., +50000) zero
#define PREP_CAST 1600000
#define PREP_TR   327680
__global__ void k_prep(const float* __restrict__ x,
                       __hip_bfloat16* __restrict__ xb, unsigned char* __restrict__ x8,
                       const float* __restrict__ s0, const float* __restrict__ s1,
                       const float* __restrict__ s2, const float* __restrict__ s3,
                       const float* __restrict__ s4, const float* __restrict__ s5,
                       __hip_bfloat16* __restrict__ d0, __hip_bfloat16* __restrict__ d1,
                       __hip_bfloat16* __restrict__ d2, __hip_bfloat16* __restrict__ d3,
                       __hip_bfloat16* __restrict__ d4, __hip_bfloat16* __restrict__ d5,
                       int* __restrict__ cnt) {
    int f = blockIdx.x * blockDim.x + threadIdx.x;
    if (f < PREP_CAST) {
        float4 v = *(const float4*)(x + f * 4);
        union { uint2 u; unsigned short s[4]; } ob;
        ob.s[0] = __bfloat16_as_ushort(__float2bfloat16(v.x));
        ob.s[1] = __bfloat16_as_ushort(__float2bfloat16(v.y));
        ob.s[2] = __bfloat16_as_ushort(__float2bfloat16(v.z));
        ob.s[3] = __bfloat16_as_ushort(__float2bfloat16(v.w));
        *(uint2*)(xb + f * 4) = ob.u;
        int p = __builtin_amdgcn_cvt_pk_fp8_f32(v.x, v.y, 0, false);
        p = __builtin_amdgcn_cvt_pk_fp8_f32(v.z, v.w, p, true);
        *(int*)(x8 + f * 4) = p;
    } else if (f < PREP_CAST + PREP_TR) {
        int r = f - PREP_CAST;
        const float* src; __hip_bfloat16* dst; int K; int i;
        if (r < 65536) {
            K = 128;
            if (r < 32768) { src = s0; dst = d0; i = r; }
            else           { src = s1; dst = d1; i = r - 32768; }
        } else {
            K = 256;
            int q = r - 65536;
            int wsel = q >> 16;
            i = q & 65535;
            src = (wsel == 0) ? s2 : (wsel == 1) ? s3 : (wsel == 2) ? s4 : s5;
            dst = (wsel == 0) ? d2 : (wsel == 1) ? d3 : (wsel == 2) ? d4 : d5;
        }
        int k = i >> 8;
        int nn = i & 255;
        dst[nn * K + k] = __float2bfloat16(src[i]);
    } else {
        int i = f - PREP_CAST - PREP_TR;
        if (i < NNODES) cnt[i] = 0;
    }
}

// ---------------- mean aggregation over fp8 table -> bf16 mean ----------
// D feats/row (1 B each). CPL = D/16 lanes per row (16B=16 feats per lane);
// R = 64/CPL neighbors per sub-step; U unroll -> U*R in flight.
template <int D, int U>
__global__ void k_meanf8(const unsigned char* __restrict__ x8,
                         const int* __restrict__ rowptr, const int* __restrict__ col,
                         __hip_bfloat16* __restrict__ mean, int n) {
    constexpr int CPL = D / 16;
    constexpr int R = 64 / CPL;
    int gw = (blockIdx.x * blockDim.x + threadIdx.x) >> 6;
    int lane = threadIdx.x & 63;
    if (gw >= n) return;
    int beg = rowptr[gw], end = rowptr[gw + 1];
    int sub = lane / CPL;
    int fpos = lane % CPL;
    const uint4* base = (const uint4*)x8;   // CPL uint4 per row

    float acc[16];
#pragma unroll
    for (int j = 0; j < 16; j++) acc[j] = 0.f;

    for (int p0 = beg; p0 < end; p0 += U * R) {
        int idx[U]; bool ok[U];
#pragma unroll
        for (int u = 0; u < U; u++) {
            int p = p0 + u * R + sub;
            ok[u] = (p < end);
            idx[u] = ok[u] ? col[p] : 0;
        }
        uint4 v[U];
#pragma unroll
        for (int u = 0; u < U; u++) {
            uint4 t = {0u, 0u, 0u, 0u};
            if (ok[u]) t = base[(size_t)idx[u] * CPL + fpos];
            v[u] = t;
        }
#pragma unroll
        for (int u = 0; u < U; u++) {
            const unsigned int uu[4] = {v[u].x, v[u].y, v[u].z, v[u].w};
#pragma unroll
            for (int q = 0; q < 4; q++) {
                f32x2 lo = __builtin_amdgcn_cvt_pk_f32_fp8(uu[q], false);
                f32x2 hi = __builtin_amdgcn_cvt_pk_f32_fp8(uu[q], true);
                acc[4 * q + 0] += lo.x;
                acc[4 * q + 1] += lo.y;
                acc[4 * q + 2] += hi.x;
                acc[4 * q + 3] += hi.y;
            }
        }
    }

    // reduce across neighbor slots (lanes sharing fpos)
    if constexpr (R >= 8) {
#pragma unroll
        for (int j = 0; j < 16; j++) acc[j] += __shfl_xor(acc[j], 8, 64);
    }
#pragma unroll
    for (int j = 0; j < 16; j++) acc[j] += __shfl_xor(acc[j], 16, 64);
#pragma unroll
    for (int j = 0; j < 16; j++) acc[j] += __shfl_xor(acc[j], 32, 64);

    if (sub == 0) {
        float inv = (end > beg) ? 1.f / (float)(end - beg) : 0.f;
        union { uint4 v[2]; unsigned short s[16]; } o;
#pragma unroll
        for (int j = 0; j < 16; j++)
            o.s[j] = __bfloat16_as_ushort(__float2bfloat16(acc[j] * inv));
        uint4* dst = (uint4*)(mean + (size_t)gw * D + fpos * 16);
        dst[0] = o.v[0];
        dst[1] = o.v[1];
    }
}

// ---------------- fused GEMM + BN (+ReLU), 128x256 tile, optional fp8 copy --
// out[n,256] = act( (A1@W1 + A2@W2 + bl - rm) * scale + shift )
template <int K, typename OutT, int RELU, int W8>
__launch_bounds__(256, 2)
__global__ void k_gemm2(const __hip_bfloat16* __restrict__ A1,
                        const __hip_bfloat16* __restrict__ A2,
                        const __hip_bfloat16* __restrict__ W1t,
                        const __hip_bfloat16* __restrict__ W2t,
                        const float* __restrict__ bl,
                        const float* __restrict__ g,
                        const float* __restrict__ bb,
                        const float* __restrict__ rm,
                        const float* __restrict__ rv,
                        OutT* __restrict__ out, unsigned char* __restrict__ out8,
                        int n) {
    __shared__ __hip_bfloat16 As1[128 * 32];
    __shared__ __hip_bfloat16 As2[128 * 32];
    __shared__ __hip_bfloat16 Bs1[256 * 32];
    __shared__ __hip_bfloat16 Bs2[256 * 32];
    int tid = threadIdx.x;
    int lane = tid & 63;
    int w = tid >> 6;
    int quad = lane >> 4;
    int ml = lane & 15;
    int rowBase = blockIdx.x * 128;
    int wr = w >> 1, wc = w & 1;

    f32x4 acc[4][8];
#pragma unroll
    for (int i = 0; i < 4; i++)
#pragma unroll
        for (int t = 0; t < 8; t++) acc[i][t] = {0.f, 0.f, 0.f, 0.f};

    int srow = tid >> 2;
    int sbyte = (tid & 3) * 16;

    for (int k0 = 0; k0 < K; k0 += 32) {
        __syncthreads();
#pragma unroll
        for (int h = 0; h < 2; h++) {
            int r = srow + h * 64;
            int grow = rowBase + r; if (grow >= n) grow = n - 1;
            load_lds16((const char*)(A1 + (size_t)grow * K + k0) + sbyte,
                       (char*)As1 + r * 64 + sbyte);
            load_lds16((const char*)(A2 + (size_t)grow * K + k0) + sbyte,
                       (char*)As2 + r * 64 + sbyte);
        }
#pragma unroll
        for (int h = 0; h < 4; h++) {
            int c = srow + h * 64;
            load_lds16((const char*)(W1t + (size_t)c * K + k0) + sbyte,
                       (char*)Bs1 + c * 64 + sbyte);
            load_lds16((const char*)(W2t + (size_t)c * K + k0) + sbyte,
                       (char*)Bs2 + c * 64 + sbyte);
        }
        __syncthreads();

        short8v af1[4], af2[4];
#pragma unroll
        for (int i = 0; i < 4; i++) {
            af1[i] = *(const short8v*)(As1 + (wr * 64 + i * 16 + ml) * 32 + quad * 8);
            af2[i] = *(const short8v*)(As2 + (wr * 64 + i * 16 + ml) * 32 + quad * 8);
        }
#pragma unroll
        for (int t = 0; t < 8; t++) {
            short8v bf1 = *(const short8v*)(Bs1 + (wc * 128 + t * 16 + ml) * 32 + quad * 8);
            short8v bf2 = *(const short8v*)(Bs2 + (wc * 128 + t * 16 + ml) * 32 + quad * 8);
#pragma unroll
            for (int i = 0; i < 4; i++) {
                acc[i][t] = __builtin_amdgcn_mfma_f32_16x16x32_bf16(af1[i], bf1, acc[i][t], 0, 0, 0);
                acc[i][t] = __builtin_amdgcn_mfma_f32_16x16x32_bf16(af2[i], bf2, acc[i][t], 0, 0, 0);
            }
        }
    }

#pragma unroll
    for (int t = 0; t < 8; t++) {
        int c = wc * 128 + t * 16 + ml;
        float sv = g[c] * rsqrtf(rv[c] + BN_EPS);
        float tv = (bl[c] - rm[c]) * sv + bb[c];
#pragma unroll
        for (int i = 0; i < 4; i++) {
            int row0 = rowBase + wr * 64 + i * 16 + quad * 4;
#pragma unroll
            for (int r = 0; r < 4; r++) {
                int row = row0 + r;
                if (row < n) {
                    float v = acc[i][t][r] * sv + tv;
                    if (RELU) v = fmaxf(v, 0.f);
                    if constexpr (sizeof(OutT) == 2)
                        out[(size_t)row * HID + c] = (OutT)__float2bfloat16(v);
                    else
                        out[(size_t)row * HID + c] = (OutT)v;
                    if constexpr (W8) {
                        int p = __builtin_amdgcn_cvt_pk_fp8_f32(v, v, 0, false);
                        out8[(size_t)row * HID + c] = (unsigned char)(p & 0xFF);
                    }
                }
            }
        }
    }
}

extern "C" void kernel_launch(void* const* d_in, const int* in_sizes, int n_in,
                              void* d_out, int out_size, void* d_ws, size_t ws_size,
                              hipStream_t stream) {
    const float* x = (const float*)d_in[0];
    const int* ei = (const int*)d_in[1];
    const float *Wl[3], *blv[3], *Wr[3], *g[3], *bb[3], *rm[3], *rv[3];
    for (int i = 0; i < 3; i++) {
        int b = 2 + i * 7;
        Wl[i]  = (const float*)d_in[b + 0];
        blv[i] = (const float*)d_in[b + 1];
        Wr[i]  = (const float*)d_in[b + 2];
        g[i]   = (const float*)d_in[b + 3];
        bb[i]  = (const float*)d_in[b + 4];
        rm[i]  = (const float*)d_in[b + 5];
        rv[i]  = (const float*)d_in[b + 6];
    }

    // scratch inside d_out (fully overwritten by the final GEMM):
    char* ob = (char*)d_out;
    __hip_bfloat16* xb = (__hip_bfloat16*)ob;                              // 12.8 MB
    __hip_bfloat16* h0 = (__hip_bfloat16*)(ob + (size_t)NNODES * 128 * 2); // 25.6 MB

    char* w = (char*)d_ws;
    size_t off = 0;
    auto alloc = [&](size_t bytes) {
        void* p = w + off;
        off += (bytes + 255) & ~(size_t)255;
        return p;
    };
    int* rowptr = (int*)alloc((NNODES + 1) * sizeof(int));
    int* cnt    = (int*)alloc(NNODES * sizeof(int));
    int* loc    = (int*)alloc(NNODES * sizeof(int));
    int* bsum   = (int*)alloc(SCAN_B * sizeof(int));
    int* rank   = (int*)alloc(NEDGES * sizeof(int));
    int* col    = (int*)alloc(NEDGES * sizeof(int));
    __hip_bfloat16* meanb = (__hip_bfloat16*)alloc((size_t)NNODES * HID * 2);
    __hip_bfloat16* h1    = (__hip_bfloat16*)alloc((size_t)NNODES * HID * 2);
    unsigned char* x8   = (unsigned char*)alloc((size_t)NNODES * 128);
    unsigned char* h0f8 = (unsigned char*)alloc((size_t)NNODES * HID);
    unsigned char* h1f8 = (unsigned char*)alloc((size_t)NNODES * HID);
    __hip_bfloat16* Wt[6];
    int Ks[6] = {128, 128, 256, 256, 256, 256};
    for (int i = 0; i < 6; i++) Wt[i] = (__hip_bfloat16*)alloc((size_t)Ks[i] * HID * 2);

    // fused prep: cast x (bf16 + fp8), transpose weights, zero cnt
    int prepTotal = PREP_CAST + PREP_TR + NNODES;
    k_prep<<<(prepTotal + 255) / 256, 256, 0, stream>>>(
        x, xb, x8, Wl[0], Wr[0], Wl[1], Wr[1], Wl[2], Wr[2],
        Wt[0], Wt[1], Wt[2], Wt[3], Wt[4], Wt[5], cnt);

    // CSR build
    k_countrank<<<(NEDGES + 255) / 256, 256, 0, stream>>>(ei, cnt, rank, NEDGES);
    k_bsum<<<SCAN_B, 256, 0, stream>>>(cnt, loc, bsum, NNODES);
    k_bscan<<<1, 256, 0, stream>>>(bsum, SCAN_B);
    k_addoff<<<SCAN_B, 256, 0, stream>>>(loc, bsum, rowptr, NNODES, NEDGES);
    k_fill2<<<(NEDGES + 255) / 256, 256, 0, stream>>>(ei, rowptr, rank, col, NEDGES);

    int meanBlocks = (NNODES * 64 + 255) / 256;      // one wave per node
    int gemmBlocks = (NNODES + 127) / 128;

    // layer 0 (K=128): fp8 gather (CPL=8, R=8, U=2 -> 16 in flight)
    k_meanf8<128, 2><<<meanBlocks, 256, 0, stream>>>(x8, rowptr, col, meanb, NNODES);
    k_gemm2<128, __hip_bfloat16, 1, 1><<<gemmBlocks, 256, 0, stream>>>(meanb, xb, Wt[0], Wt[1],
        blv[0], g[0], bb[0], rm[0], rv[0], h0, h0f8, NNODES);

    // layer 1 (K=256): fp8 gather (CPL=16, R=4, U=4 -> 16 in flight)
    k_meanf8<256, 4><<<meanBlocks, 256, 0, stream>>>(h0f8, rowptr, col, meanb, NNODES);
    k_gemm2<256, __hip_bfloat16, 1, 1><<<gemmBlocks, 256, 0, stream>>>(meanb, h0, Wt[2], Wt[3],
        blv[1], g[1], bb[1], rm[1], rv[1], h1, h1f8, NNODES);

    // layer 2 (K=256, no relu) -> f32 d_out
    k_meanf8<256, 4><<<meanBlocks, 256, 0, stream>>>(h1f8, rowptr, col, meanb, NNODES);
    k_gemm2<256, float, 0, 0><<<gemmBlocks, 256, 0, stream>>>(meanb, h1, Wt[4], Wt[5],
        blv[2], g[2], bb[2], rm[2], rv[2], (float*)d_out, (unsigned char*)nullptr, NNODES);
}